// Round 7
// baseline (163.405 us; speedup 1.0000x reference)
//
#include <hip/hip_runtime.h>

typedef unsigned short u16;
typedef unsigned char u8;
typedef __attribute__((ext_vector_type(2))) float floatx2;
typedef __attribute__((ext_vector_type(4))) float floatx4;
typedef __attribute__((ext_vector_type(8))) __bf16 bf16x8;
typedef __attribute__((ext_vector_type(2))) unsigned short us2;
typedef __attribute__((ext_vector_type(4))) unsigned short us4;
typedef __attribute__((ext_vector_type(8))) unsigned short us8;

static __device__ __forceinline__ float b2f(u16 v) {
    union { unsigned u; float f; } x; x.u = ((unsigned)v) << 16; return x.f;
}
static __device__ __forceinline__ u16 f2b(float f) {
    union { float f; unsigned u; } x; x.f = f;
    unsigned u = x.u;
    return (u16)((u + 0x7fffu + ((u >> 16) & 1u)) >> 16);
}

#define GLOAD_LDS16(g, l) __builtin_amdgcn_global_load_lds( \
    (const __attribute__((address_space(1))) void*)(g),     \
    (__attribute__((address_space(3))) void*)(l), 16, 0, 0)

#define CAP 64
#define SPILLMAX 4096

// Per-block dtype self-detection (see R5 notes): P(misdetect fp32) ~ 1e-65.
static __device__ __forceinline__ int detect_blk(const u16* __restrict__ p,
                                                 int nelem, int* sh) {
    if (threadIdx.x == 0) *sh = 0;
    __syncthreads();
    const int lim = nelem < 512 ? nelem : 512;
    int found = 0;
    for (int j = threadIdx.x; 2 * j < lim; j += 256) {
        unsigned v = p[2 * j] & 0x7fffu;
        if (v >= 0x4280u) found = 1;  // |bf16(bits)| >= 64.0
    }
    if (found) atomicOr(sh, 1);
    __syncthreads();
    return *sh;
}

// ================= D1: buckets + all conversions (self-detecting) ================
__global__ __launch_bounds__(256) void k_d1(
    const int* __restrict__ src, const int* __restrict__ dst, int E, int Nn,
    int* __restrict__ cnt, int* __restrict__ bucket,
    int* __restrict__ nspill, int* __restrict__ spill,
    const void* __restrict__ h, const void* __restrict__ W1,
    const void* __restrict__ b1, const void* __restrict__ W2,
    const void* __restrict__ b2,
    u16* __restrict__ Hb, u16* __restrict__ W1T, u16* __restrict__ W2T,
    u16* __restrict__ b1c, u16* __restrict__ b2c, int* __restrict__ flags,
    int nFill, int nHb) {
    __shared__ u16 tile[32][33];
    __shared__ int sh;
    const int b = blockIdx.x;
    const int t = threadIdx.x;

    if (b < nFill) {  // -------- bucket fill --------
        int e = b * 256 + t;
        if (e < E) {
            int d = dst[e], s = src[e];
            if ((unsigned)d < (unsigned)Nn && (unsigned)s < (unsigned)Nn) {
                int p = atomicAdd(&cnt[d], 1);
                if (p < CAP) bucket[d * CAP + p] = s;
                else {
                    int q = atomicAdd(nspill, 1);
                    if (q < SPILLMAX) { spill[2 * q] = d; spill[2 * q + 1] = s; }
                }
            }
        }
        return;
    }
    if (b < nFill + nHb) {  // -------- Hb cvt --------
        const int f = detect_blk((const u16*)h, Nn * 512, &sh);
        int i = ((b - nFill) * 256 + t) * 8;
        if (i >= Nn * 512) return;
        if (f) {
            const float* s = (const float*)h;
            us8 o;
#pragma unroll
            for (int k = 0; k < 8; ++k) o[k] = f2b(s[i + k]);
            *(us8*)(Hb + i) = o;
        } else {
            *(us8*)(Hb + i) = *(const us8*)((const u16*)h + i);
        }
        return;
    }
    if (b < nFill + nHb + 512) {  // -------- W1 [1024,512] -> W1T [1024,512] --------
        const int f = detect_blk((const u16*)W1, 1024 * 512, &sh);
        int sub = b - nFill - nHb;
        int half = sub >> 8, idx = sub & 255;
        const int bx = (idx & 15) * 32, by = (idx >> 4) * 32;
        const int koff = half * 512, noff = half * 512;
        const int tx = t & 31, ty = t >> 5;
        for (int i = ty; i < 32; i += 8) {
            long id = (long)(koff + by + i) * 512 + (bx + tx);
            tile[i][tx] = f ? f2b(((const float*)W1)[id]) : ((const u16*)W1)[id];
        }
        __syncthreads();
        for (int i = ty; i < 32; i += 8)
            W1T[(long)(noff + bx + i) * 512 + (by + tx)] = tile[tx][i];
        return;
    }
    if (b < nFill + nHb + 640) {  // -------- W2 [1024,128] -> W2T [256,512] --------
        const int f = detect_blk((const u16*)W2, 1024 * 128, &sh);
        int sub = b - nFill - nHb - 512;
        int half = sub >> 6, idx = sub & 63;
        const int bx = (idx & 3) * 32, by = (idx >> 2) * 32;
        const int koff = half * 512, noff = half * 128;
        const int tx = t & 31, ty = t >> 5;
        for (int i = ty; i < 32; i += 8) {
            long id = (long)(koff + by + i) * 128 + (bx + tx);
            tile[i][tx] = f ? f2b(((const float*)W2)[id]) : ((const u16*)W2)[id];
        }
        __syncthreads();
        for (int i = ty; i < 32; i += 8)
            W2T[(long)(noff + bx + i) * 512 + (by + tx)] = tile[tx][i];
        return;
    }
    // -------- biases + out-dtype flag --------
    {
        const int f1 = detect_blk((const u16*)b1, 512, &sh);
        for (int i = t; i < 512; i += 256)
            b1c[i] = f1 ? f2b(((const float*)b1)[i]) : ((const u16*)b1)[i];
        const int f2 = detect_blk((const u16*)b2, 128, &sh);
        if (t < 128)
            b2c[t] = f2 ? f2b(((const float*)b2)[t]) : ((const u16*)b2)[t];
        const int fh = detect_blk((const u16*)h, Nn * 512, &sh);
        if (t == 0) flags[0] = fh;
    }
}

// ================= GEMM accumulate core (device) =================================
__device__ __forceinline__ void gemm_acc(const u16* __restrict__ A,
                                         const u16* __restrict__ Bt,
                                         long brow, int bcol,
                                         floatx4 acc[4][4], u16* lA, u16* lB) {
    const int tid = threadIdx.x;
    const int wv = tid >> 6;
    const int ln = tid & 63;
    const int wr = (wv >> 1) * 64;
    const int wc = (wv & 1) * 64;
    const int lrow = ln >> 2;
    const int lk = (ln & 3) * 8;
    const int m0 = ln & 15;
    const int kq = (ln >> 4) * 8;

#pragma unroll
    for (int i = 0; i < 4; ++i)
#pragma unroll
        for (int j = 0; j < 4; ++j) acc[i][j] = (floatx4){0.f, 0.f, 0.f, 0.f};

    for (int kt = 0; kt < 512; kt += 32) {
#pragma unroll
        for (int i = 0; i < 2; ++i) {
            const int c = i * 4 + wv;
            const int row = c * 16 + lrow;
            GLOAD_LDS16(A + (brow + row) * 512 + kt + lk, lA + c * 512);
            GLOAD_LDS16(Bt + (long)(bcol + row) * 512 + kt + lk, lB + c * 512);
        }
        __syncthreads();
        bf16x8 af[4], bf[4];
#pragma unroll
        for (int i = 0; i < 4; ++i)
            af[i] = *(const bf16x8*)(lA + (wr + i * 16 + m0) * 32 + kq);
#pragma unroll
        for (int j = 0; j < 4; ++j)
            bf[j] = *(const bf16x8*)(lB + (wc + j * 16 + m0) * 32 + kq);
#pragma unroll
        for (int i = 0; i < 4; ++i)
#pragma unroll
            for (int j = 0; j < 4; ++j)
                acc[i][j] = __builtin_amdgcn_mfma_f32_16x16x32_bf16(af[i], bf[j],
                                                                    acc[i][j], 0, 0, 0);
        __syncthreads();
    }
}

// ================= D2: GEMM1 ([C1s(bf16) | P1(fp8)] = Hb @ W1T^T) ================
__global__ __launch_bounds__(256) void k_gemm1(
    const u16* __restrict__ A, const u16* __restrict__ Bt,
    u16* __restrict__ C1s, u8* __restrict__ P1, int Mstore) {
    __shared__ __align__(16) u16 lA[128 * 32];
    __shared__ __align__(16) u16 lB[128 * 32];
    const int by = blockIdx.y;          // 0..7
    const int bcol = by * 128;
    const long brow = (long)blockIdx.x * 128;
    floatx4 acc[4][4];
    gemm_acc(A, Bt, brow, bcol, acc, lA, lB);

    const int ln = threadIdx.x & 63;
    const int wv = threadIdx.x >> 6;
    const int wr = (wv >> 1) * 64;
    const int wc = (wv & 1) * 64;
    const int m0 = ln & 15;
    const int q4 = (ln >> 4) * 4;
    if (by < 4) {  // self half -> bf16, ld 512
#pragma unroll
        for (int i = 0; i < 4; ++i)
#pragma unroll
            for (int r = 0; r < 4; ++r) {
                long row = brow + wr + i * 16 + q4 + r;
                if (row < Mstore) {
#pragma unroll
                    for (int j = 0; j < 4; ++j)
                        C1s[row * 512 + (bcol + wc + j * 16 + m0)] = f2b(acc[i][j][r]);
                }
            }
    } else {       // agg half -> fp8 e4m3 bytes, ld 512
        const int coff = bcol - 512;
#pragma unroll
        for (int i = 0; i < 4; ++i)
#pragma unroll
            for (int r = 0; r < 4; ++r) {
                long row = brow + wr + i * 16 + q4 + r;
                if (row < Mstore) {
#pragma unroll
                    for (int j = 0; j < 4; ++j) {
                        float v = acc[i][j][r];
                        int pk = __builtin_amdgcn_cvt_pk_fp8_f32(v, v, 0, false);
                        P1[row * 512 + (coff + wc + j * 16 + m0)] = (u8)(pk & 0xff);
                    }
                }
            }
    }
}

// ================= D4: GEMM2 ([C2s|P2] = h1 @ W2T^T, bf16) =======================
__global__ __launch_bounds__(256) void k_gemm2(
    const u16* __restrict__ A, const u16* __restrict__ Bt,
    u16* __restrict__ C2s, u16* __restrict__ P2, int Mstore) {
    __shared__ __align__(16) u16 lA[128 * 32];
    __shared__ __align__(16) u16 lB[128 * 32];
    const int by = blockIdx.y;          // 0: self, 1: agg
    const long brow = (long)blockIdx.x * 128;
    floatx4 acc[4][4];
    gemm_acc(A, Bt, brow, by * 128, acc, lA, lB);

    u16* C = by ? P2 : C2s;
    const int ln = threadIdx.x & 63;
    const int wv = threadIdx.x >> 6;
    const int wr = (wv >> 1) * 64;
    const int wc = (wv & 1) * 64;
    const int m0 = ln & 15;
    const int q4 = (ln >> 4) * 4;
#pragma unroll
    for (int i = 0; i < 4; ++i)
#pragma unroll
        for (int r = 0; r < 4; ++r) {
            long row = brow + wr + i * 16 + q4 + r;
            if (row < Mstore) {
#pragma unroll
                for (int j = 0; j < 4; ++j)
                    C[row * 128 + (wc + j * 16 + m0)] = f2b(acc[i][j][r]);
            }
        }
}

// ================= D3: h1 = relu(C1s + mean(P1fp8[nbrs]) + b1) ===================
// 256 threads = 2 nodes; 4 fp8 cols/thread (4B coalesced); 4-deep gather unroll
__global__ __launch_bounds__(256) void agg_h1(const u8* __restrict__ P1,
                                              const u16* __restrict__ C1s,
                                              const u16* __restrict__ b1c,
                                              const int* __restrict__ cnt,
                                              const int* __restrict__ bucket,
                                              const int* __restrict__ nspill,
                                              const int* __restrict__ spill,
                                              u16* __restrict__ h1, int Nn) {
    const int n = blockIdx.x * 2 + (threadIdx.x >> 7);
    const int t = threadIdx.x & 127;
    if (n >= Nn) return;
    const int c = cnt[n];
    const int inb = c < CAP ? c : CAP;
    const int* bk = bucket + (long)n * CAP;
    float a0 = 0.f, a1 = 0.f, a2 = 0.f, a3 = 0.f;
    int e = 0;
    for (; e + 3 < inb; e += 4) {
        int s0 = bk[e], s1 = bk[e + 1], s2 = bk[e + 2], s3 = bk[e + 3];
        unsigned w0 = *(const unsigned*)(P1 + (long)s0 * 512 + t * 4);
        unsigned w1 = *(const unsigned*)(P1 + (long)s1 * 512 + t * 4);
        unsigned w2 = *(const unsigned*)(P1 + (long)s2 * 512 + t * 4);
        unsigned w3 = *(const unsigned*)(P1 + (long)s3 * 512 + t * 4);
        floatx2 l0 = __builtin_amdgcn_cvt_pk_f32_fp8(w0, false);
        floatx2 h0 = __builtin_amdgcn_cvt_pk_f32_fp8(w0, true);
        floatx2 l1 = __builtin_amdgcn_cvt_pk_f32_fp8(w1, false);
        floatx2 h1v = __builtin_amdgcn_cvt_pk_f32_fp8(w1, true);
        floatx2 l2 = __builtin_amdgcn_cvt_pk_f32_fp8(w2, false);
        floatx2 h2 = __builtin_amdgcn_cvt_pk_f32_fp8(w2, true);
        floatx2 l3 = __builtin_amdgcn_cvt_pk_f32_fp8(w3, false);
        floatx2 h3 = __builtin_amdgcn_cvt_pk_f32_fp8(w3, true);
        a0 += (l0[0] + l1[0]) + (l2[0] + l3[0]);
        a1 += (l0[1] + l1[1]) + (l2[1] + l3[1]);
        a2 += (h0[0] + h1v[0]) + (h2[0] + h3[0]);
        a3 += (h0[1] + h1v[1]) + (h2[1] + h3[1]);
    }
    for (; e < inb; ++e) {
        int s0 = bk[e];
        unsigned w0 = *(const unsigned*)(P1 + (long)s0 * 512 + t * 4);
        floatx2 l0 = __builtin_amdgcn_cvt_pk_f32_fp8(w0, false);
        floatx2 h0 = __builtin_amdgcn_cvt_pk_f32_fp8(w0, true);
        a0 += l0[0]; a1 += l0[1]; a2 += h0[0]; a3 += h0[1];
    }
    const int ns = *nspill;             // 0 in practice
    if (ns > 0) {
        int lim = ns < SPILLMAX ? ns : SPILLMAX;
        for (int q = 0; q < lim; ++q) {
            if (spill[2 * q] == n) {
                int s0 = spill[2 * q + 1];
                unsigned w0 = *(const unsigned*)(P1 + (long)s0 * 512 + t * 4);
                floatx2 l0 = __builtin_amdgcn_cvt_pk_f32_fp8(w0, false);
                floatx2 h0 = __builtin_amdgcn_cvt_pk_f32_fp8(w0, true);
                a0 += l0[0]; a1 += l0[1]; a2 += h0[0]; a3 += h0[1];
            }
        }
    }
    float inv = 1.0f / (float)(c > 1 ? c : 1);
    us4 sf = *(const us4*)(C1s + (long)n * 512 + t * 4);
    us4 bv = *(const us4*)(b1c + t * 4);
    us4 o;
    o[0] = f2b(fmaxf(b2f(sf[0]) + a0 * inv + b2f(bv[0]), 0.f));
    o[1] = f2b(fmaxf(b2f(sf[1]) + a1 * inv + b2f(bv[1]), 0.f));
    o[2] = f2b(fmaxf(b2f(sf[2]) + a2 * inv + b2f(bv[2]), 0.f));
    o[3] = f2b(fmaxf(b2f(sf[3]) + a3 * inv + b2f(bv[3]), 0.f));
    *(us4*)(h1 + (long)n * 512 + t * 4) = o;
}

// ================= D5: out = C2s + mean(P2[nbrs]) + b2 ===========================
__global__ __launch_bounds__(256) void agg_out(const u16* __restrict__ P2,
                                               const u16* __restrict__ C2s,
                                               const u16* __restrict__ b2c,
                                               const int* __restrict__ cnt,
                                               const int* __restrict__ bucket,
                                               const int* __restrict__ nspill,
                                               const int* __restrict__ spill,
                                               void* __restrict__ outv, int Nn,
                                               const int* __restrict__ flags) {
    const int n = blockIdx.x * 4 + (threadIdx.x >> 6);
    const int l = threadIdx.x & 63;
    if (n >= Nn) return;
    const int c = cnt[n];
    const int inb = c < CAP ? c : CAP;
    const int* bk = bucket + (long)n * CAP;
    float a0 = 0.f, a1 = 0.f;
    int e = 0;
    for (; e + 3 < inb; e += 4) {
        int s0 = bk[e], s1 = bk[e + 1], s2 = bk[e + 2], s3 = bk[e + 3];
        us2 v0 = *(const us2*)(P2 + (long)s0 * 128 + l * 2);
        us2 v1 = *(const us2*)(P2 + (long)s1 * 128 + l * 2);
        us2 v2 = *(const us2*)(P2 + (long)s2 * 128 + l * 2);
        us2 v3 = *(const us2*)(P2 + (long)s3 * 128 + l * 2);
        a0 += (b2f(v0[0]) + b2f(v1[0])) + (b2f(v2[0]) + b2f(v3[0]));
        a1 += (b2f(v0[1]) + b2f(v1[1])) + (b2f(v2[1]) + b2f(v3[1]));
    }
    for (; e < inb; ++e) {
        int s0 = bk[e];
        us2 v0 = *(const us2*)(P2 + (long)s0 * 128 + l * 2);
        a0 += b2f(v0[0]); a1 += b2f(v0[1]);
    }
    const int ns = *nspill;
    if (ns > 0) {
        int lim = ns < SPILLMAX ? ns : SPILLMAX;
        for (int q = 0; q < lim; ++q) {
            if (spill[2 * q] == n) {
                int s0 = spill[2 * q + 1];
                us2 v0 = *(const us2*)(P2 + (long)s0 * 128 + l * 2);
                a0 += b2f(v0[0]); a1 += b2f(v0[1]);
            }
        }
    }
    float inv = 1.0f / (float)(c > 1 ? c : 1);
    us2 sf = *(const us2*)(C2s + (long)n * 128 + l * 2);
    us2 bv = *(const us2*)(b2c + l * 2);
    float o0 = b2f(sf[0]) + a0 * inv + b2f(bv[0]);
    float o1 = b2f(sf[1]) + a1 * inv + b2f(bv[1]);
    if (flags[0]) {
        float* o = (float*)outv + (long)n * 128 + l * 2;
        o[0] = o0; o[1] = o1;
    } else {
        us2 ob; ob[0] = f2b(o0); ob[1] = f2b(o1);
        *(us2*)((u16*)outv + (long)n * 128 + l * 2) = ob;
    }
}

// ================= launch ========================================================
extern "C" void kernel_launch(void* const* d_in, const int* in_sizes, int n_in,
                              void* d_out, int out_size, void* d_ws, size_t ws_size,
                              hipStream_t stream) {
    const int D = 512, NCLS = 128;
    const int Nn = in_sizes[0] / D;            // 10000
    const int E  = in_sizes[5];                // 160000
    const int mtiles = (Nn + 127) / 128;       // 79
    const int Mpad = mtiles * 128;             // 10112
    const int nFill = (E + 255) / 256;         // 625
    const int nHb = (Nn * D / 8 + 255) / 256;  // 2500

    const int* src = (const int*)d_in[5];
    const int* dst = (const int*)d_in[6];

    char* p = (char*)d_ws;
    u16* Hb  = (u16*)p; p += (size_t)Mpad * D * 2;
    u16* h1  = (u16*)p; p += (size_t)Mpad * D * 2;
    u16* C1s = (u16*)p; p += (size_t)Mpad * D * 2;
    u8*  P1  = (u8*)p;  p += (size_t)Mpad * D;        // fp8 e4m3
    u16* C2s = (u16*)p; p += (size_t)Mpad * NCLS * 2;
    u16* P2  = (u16*)p; p += (size_t)Mpad * NCLS * 2;
    u16* W1T = (u16*)p; p += (size_t)1024 * D * 2;
    u16* W2T = (u16*)p; p += (size_t)256 * D * 2;
    u16* b1c = (u16*)p; p += 1024;
    u16* b2c = (u16*)p; p += 1024;
    int* flags  = (int*)p; p += 256;
    int* cnt    = (int*)p; p += (size_t)(Nn + 60) * 4;
    int* nspill = cnt + Nn;
    int* bucket = (int*)p; p += (size_t)Nn * CAP * 4;
    int* spill  = (int*)p; p += (size_t)SPILLMAX * 2 * 4;

    hipMemsetAsync(cnt, 0, (size_t)(Nn + 60) * 4, stream);

    // D1: buckets + all conversions
    k_d1<<<nFill + nHb + 641, 256, 0, stream>>>(
        src, dst, E, Nn, cnt, bucket, nspill, spill,
        d_in[0], d_in[1], d_in[2], d_in[3], d_in[4],
        Hb, W1T, W2T, b1c, b2c, flags, nFill, nHb);

    // D2: [C1s(bf16) | P1(fp8)] = Hb @ W1T^T
    k_gemm1<<<dim3(mtiles, 8), 256, 0, stream>>>(Hb, W1T, C1s, P1, Nn);

    // D3: h1 = relu(C1s + mean(P1[nbrs]) + b1)
    agg_h1<<<(Nn + 1) / 2, 256, 0, stream>>>(P1, C1s, b1c, cnt, bucket,
                                             nspill, spill, h1, Nn);

    // D4: [C2s|P2] = h1 @ W2T^T
    k_gemm2<<<dim3(mtiles, 2), 256, 0, stream>>>(h1, W2T, C2s, P2, Nn);

    // D5: out = C2s + mean(P2[nbrs]) + b2
    agg_out<<<(Nn + 3) / 4, 256, 0, stream>>>(P2, C2s, b2c, cnt, bucket,
                                              nspill, spill, d_out, Nn, flags);
}

// Round 8
// 162.437 us; speedup vs baseline: 1.0060x; 1.0060x over previous
//
#include <hip/hip_runtime.h>

typedef unsigned short u16;
typedef unsigned char u8;
typedef __attribute__((ext_vector_type(2))) float floatx2;
typedef __attribute__((ext_vector_type(4))) float floatx4;
typedef __attribute__((ext_vector_type(8))) __bf16 bf16x8;
typedef __attribute__((ext_vector_type(2))) unsigned short us2;
typedef __attribute__((ext_vector_type(4))) unsigned short us4;
typedef __attribute__((ext_vector_type(8))) unsigned short us8;
typedef __attribute__((ext_vector_type(2))) unsigned int u32x2;

static __device__ __forceinline__ float b2f(u16 v) {
    union { unsigned u; float f; } x; x.u = ((unsigned)v) << 16; return x.f;
}
static __device__ __forceinline__ u16 f2b(float f) {
    union { float f; unsigned u; } x; x.f = f;
    unsigned u = x.u;
    return (u16)((u + 0x7fffu + ((u >> 16) & 1u)) >> 16);
}

#define GLOAD_LDS16(g, l) __builtin_amdgcn_global_load_lds( \
    (const __attribute__((address_space(1))) void*)(g),     \
    (__attribute__((address_space(3))) void*)(l), 16, 0, 0)

#define CAP 64
#define SPILLMAX 4096

// Per-block dtype self-detection (see R5 notes): P(misdetect fp32) ~ 1e-65.
static __device__ __forceinline__ int detect_blk(const u16* __restrict__ p,
                                                 int nelem, int* sh) {
    if (threadIdx.x == 0) *sh = 0;
    __syncthreads();
    const int lim = nelem < 512 ? nelem : 512;
    int found = 0;
    for (int j = threadIdx.x; 2 * j < lim; j += 256) {
        unsigned v = p[2 * j] & 0x7fffu;
        if (v >= 0x4280u) found = 1;  // |bf16(bits)| >= 64.0
    }
    if (found) atomicOr(sh, 1);
    __syncthreads();
    return *sh;
}

// ================= D1: buckets + all conversions (self-detecting) ================
__global__ __launch_bounds__(256) void k_d1(
    const int* __restrict__ src, const int* __restrict__ dst, int E, int Nn,
    int* __restrict__ cnt, int* __restrict__ bucket,
    int* __restrict__ nspill, int* __restrict__ spill,
    const void* __restrict__ h, const void* __restrict__ W1,
    const void* __restrict__ b1, const void* __restrict__ W2,
    const void* __restrict__ b2,
    u16* __restrict__ Hb, u16* __restrict__ W1T, u16* __restrict__ W2T,
    u16* __restrict__ b1c, u16* __restrict__ b2c, int* __restrict__ flags,
    int nFill, int nHb) {
    __shared__ u16 tile[32][33];
    __shared__ int sh;
    const int b = blockIdx.x;
    const int t = threadIdx.x;

    if (b < nFill) {  // -------- bucket fill --------
        int e = b * 256 + t;
        if (e < E) {
            int d = dst[e], s = src[e];
            if ((unsigned)d < (unsigned)Nn && (unsigned)s < (unsigned)Nn) {
                int p = atomicAdd(&cnt[d], 1);
                if (p < CAP) bucket[d * CAP + p] = s;
                else {
                    int q = atomicAdd(nspill, 1);
                    if (q < SPILLMAX) { spill[2 * q] = d; spill[2 * q + 1] = s; }
                }
            }
        }
        return;
    }
    if (b < nFill + nHb) {  // -------- Hb cvt --------
        const int f = detect_blk((const u16*)h, Nn * 512, &sh);
        int i = ((b - nFill) * 256 + t) * 8;
        if (i >= Nn * 512) return;
        if (f) {
            const float* s = (const float*)h;
            us8 o;
#pragma unroll
            for (int k = 0; k < 8; ++k) o[k] = f2b(s[i + k]);
            *(us8*)(Hb + i) = o;
        } else {
            *(us8*)(Hb + i) = *(const us8*)((const u16*)h + i);
        }
        return;
    }
    if (b < nFill + nHb + 512) {  // -------- W1 [1024,512] -> W1T [1024,512] --------
        const int f = detect_blk((const u16*)W1, 1024 * 512, &sh);
        int sub = b - nFill - nHb;
        int half = sub >> 8, idx = sub & 255;
        const int bx = (idx & 15) * 32, by = (idx >> 4) * 32;
        const int koff = half * 512, noff = half * 512;
        const int tx = t & 31, ty = t >> 5;
        for (int i = ty; i < 32; i += 8) {
            long id = (long)(koff + by + i) * 512 + (bx + tx);
            tile[i][tx] = f ? f2b(((const float*)W1)[id]) : ((const u16*)W1)[id];
        }
        __syncthreads();
        for (int i = ty; i < 32; i += 8)
            W1T[(long)(noff + bx + i) * 512 + (by + tx)] = tile[tx][i];
        return;
    }
    if (b < nFill + nHb + 640) {  // -------- W2 [1024,128] -> W2T [256,512] --------
        const int f = detect_blk((const u16*)W2, 1024 * 128, &sh);
        int sub = b - nFill - nHb - 512;
        int half = sub >> 6, idx = sub & 63;
        const int bx = (idx & 3) * 32, by = (idx >> 2) * 32;
        const int koff = half * 512, noff = half * 128;
        const int tx = t & 31, ty = t >> 5;
        for (int i = ty; i < 32; i += 8) {
            long id = (long)(koff + by + i) * 128 + (bx + tx);
            tile[i][tx] = f ? f2b(((const float*)W2)[id]) : ((const u16*)W2)[id];
        }
        __syncthreads();
        for (int i = ty; i < 32; i += 8)
            W2T[(long)(noff + bx + i) * 512 + (by + tx)] = tile[tx][i];
        return;
    }
    // -------- biases + out-dtype flag --------
    {
        const int f1 = detect_blk((const u16*)b1, 512, &sh);
        for (int i = t; i < 512; i += 256)
            b1c[i] = f1 ? f2b(((const float*)b1)[i]) : ((const u16*)b1)[i];
        const int f2 = detect_blk((const u16*)b2, 128, &sh);
        if (t < 128)
            b2c[t] = f2 ? f2b(((const float*)b2)[t]) : ((const u16*)b2)[t];
        const int fh = detect_blk((const u16*)h, Nn * 512, &sh);
        if (t == 0) flags[0] = fh;
    }
}

// ================= GEMM accumulate core (device) =================================
__device__ __forceinline__ void gemm_acc(const u16* __restrict__ A,
                                         const u16* __restrict__ Bt,
                                         long brow, int bcol,
                                         floatx4 acc[4][4], u16* lA, u16* lB) {
    const int tid = threadIdx.x;
    const int wv = tid >> 6;
    const int ln = tid & 63;
    const int wr = (wv >> 1) * 64;
    const int wc = (wv & 1) * 64;
    const int lrow = ln >> 2;
    const int lk = (ln & 3) * 8;
    const int m0 = ln & 15;
    const int kq = (ln >> 4) * 8;

#pragma unroll
    for (int i = 0; i < 4; ++i)
#pragma unroll
        for (int j = 0; j < 4; ++j) acc[i][j] = (floatx4){0.f, 0.f, 0.f, 0.f};

    for (int kt = 0; kt < 512; kt += 32) {
#pragma unroll
        for (int i = 0; i < 2; ++i) {
            const int c = i * 4 + wv;
            const int row = c * 16 + lrow;
            GLOAD_LDS16(A + (brow + row) * 512 + kt + lk, lA + c * 512);
            GLOAD_LDS16(Bt + (long)(bcol + row) * 512 + kt + lk, lB + c * 512);
        }
        __syncthreads();
        bf16x8 af[4], bf[4];
#pragma unroll
        for (int i = 0; i < 4; ++i)
            af[i] = *(const bf16x8*)(lA + (wr + i * 16 + m0) * 32 + kq);
#pragma unroll
        for (int j = 0; j < 4; ++j)
            bf[j] = *(const bf16x8*)(lB + (wc + j * 16 + m0) * 32 + kq);
#pragma unroll
        for (int i = 0; i < 4; ++i)
#pragma unroll
            for (int j = 0; j < 4; ++j)
                acc[i][j] = __builtin_amdgcn_mfma_f32_16x16x32_bf16(af[i], bf[j],
                                                                    acc[i][j], 0, 0, 0);
        __syncthreads();
    }
}

// ================= D2: GEMM1 ([C1s(bf16) | P1(fp8)] = Hb @ W1T^T) ================
__global__ __launch_bounds__(256) void k_gemm1(
    const u16* __restrict__ A, const u16* __restrict__ Bt,
    u16* __restrict__ C1s, u8* __restrict__ P1, int Mstore) {
    __shared__ __align__(16) u16 lA[128 * 32];
    __shared__ __align__(16) u16 lB[128 * 32];
    const int by = blockIdx.y;          // 0..7
    const int bcol = by * 128;
    const long brow = (long)blockIdx.x * 128;
    floatx4 acc[4][4];
    gemm_acc(A, Bt, brow, bcol, acc, lA, lB);

    const int ln = threadIdx.x & 63;
    const int wv = threadIdx.x >> 6;
    const int wr = (wv >> 1) * 64;
    const int wc = (wv & 1) * 64;
    const int m0 = ln & 15;
    const int q4 = (ln >> 4) * 4;
    if (by < 4) {  // self half -> bf16, ld 512
#pragma unroll
        for (int i = 0; i < 4; ++i)
#pragma unroll
            for (int r = 0; r < 4; ++r) {
                long row = brow + wr + i * 16 + q4 + r;
                if (row < Mstore) {
#pragma unroll
                    for (int j = 0; j < 4; ++j)
                        C1s[row * 512 + (bcol + wc + j * 16 + m0)] = f2b(acc[i][j][r]);
                }
            }
    } else {       // agg half -> fp8 e4m3 bytes, ld 512
        const int coff = bcol - 512;
#pragma unroll
        for (int i = 0; i < 4; ++i)
#pragma unroll
            for (int r = 0; r < 4; ++r) {
                long row = brow + wr + i * 16 + q4 + r;
                if (row < Mstore) {
#pragma unroll
                    for (int j = 0; j < 4; ++j) {
                        float v = acc[i][j][r];
                        int pk = __builtin_amdgcn_cvt_pk_fp8_f32(v, v, 0, false);
                        P1[row * 512 + (coff + wc + j * 16 + m0)] = (u8)(pk & 0xff);
                    }
                }
            }
    }
}

// ================= D4: GEMM2 ([C2s|P2] = h1 @ W2T^T, bf16) =======================
__global__ __launch_bounds__(256) void k_gemm2(
    const u16* __restrict__ A, const u16* __restrict__ Bt,
    u16* __restrict__ C2s, u16* __restrict__ P2, int Mstore) {
    __shared__ __align__(16) u16 lA[128 * 32];
    __shared__ __align__(16) u16 lB[128 * 32];
    const int by = blockIdx.y;          // 0: self, 1: agg
    const long brow = (long)blockIdx.x * 128;
    floatx4 acc[4][4];
    gemm_acc(A, Bt, brow, by * 128, acc, lA, lB);

    u16* C = by ? P2 : C2s;
    const int ln = threadIdx.x & 63;
    const int wv = threadIdx.x >> 6;
    const int wr = (wv >> 1) * 64;
    const int wc = (wv & 1) * 64;
    const int m0 = ln & 15;
    const int q4 = (ln >> 4) * 4;
#pragma unroll
    for (int i = 0; i < 4; ++i)
#pragma unroll
        for (int r = 0; r < 4; ++r) {
            long row = brow + wr + i * 16 + q4 + r;
            if (row < Mstore) {
#pragma unroll
                for (int j = 0; j < 4; ++j)
                    C[row * 128 + (wc + j * 16 + m0)] = f2b(acc[i][j][r]);
            }
        }
}

// ================= D3: h1 = relu(C1s + mean(P1fp8[nbrs]) + b1) ===================
// WAVE-PER-NODE: 64 lanes cover the 512B fp8 row with ONE dwordx2 load per edge
// (was 2 wave-loads with 128 threads x 4B). 4 nodes/block; 8-deep gather unroll
// = 64B in flight per lane to cover L2/L3 latency.
__global__ __launch_bounds__(256) void agg_h1(const u8* __restrict__ P1,
                                              const u16* __restrict__ C1s,
                                              const u16* __restrict__ b1c,
                                              const int* __restrict__ cnt,
                                              const int* __restrict__ bucket,
                                              const int* __restrict__ nspill,
                                              const int* __restrict__ spill,
                                              u16* __restrict__ h1, int Nn) {
    const int n = blockIdx.x * 4 + (threadIdx.x >> 6);
    const int l = threadIdx.x & 63;
    if (n >= Nn) return;
    const int c = cnt[n];
    const int inb = c < CAP ? c : CAP;
    const int* bk = bucket + (long)n * CAP;
    float a0 = 0.f, a1 = 0.f, a2 = 0.f, a3 = 0.f;
    float a4 = 0.f, a5 = 0.f, a6 = 0.f, a7 = 0.f;
    int e = 0;
    for (; e + 7 < inb; e += 8) {
        u32x2 w[8];
#pragma unroll
        for (int q = 0; q < 8; ++q) {
            int s = bk[e + q];
            w[q] = *(const u32x2*)(P1 + (long)s * 512 + l * 8);
        }
#pragma unroll
        for (int q = 0; q < 8; ++q) {
            floatx2 f0 = __builtin_amdgcn_cvt_pk_f32_fp8(w[q][0], false);
            floatx2 f1 = __builtin_amdgcn_cvt_pk_f32_fp8(w[q][0], true);
            floatx2 f2 = __builtin_amdgcn_cvt_pk_f32_fp8(w[q][1], false);
            floatx2 f3 = __builtin_amdgcn_cvt_pk_f32_fp8(w[q][1], true);
            a0 += f0[0]; a1 += f0[1]; a2 += f1[0]; a3 += f1[1];
            a4 += f2[0]; a5 += f2[1]; a6 += f3[0]; a7 += f3[1];
        }
    }
    for (; e < inb; ++e) {
        int s = bk[e];
        u32x2 w = *(const u32x2*)(P1 + (long)s * 512 + l * 8);
        floatx2 f0 = __builtin_amdgcn_cvt_pk_f32_fp8(w[0], false);
        floatx2 f1 = __builtin_amdgcn_cvt_pk_f32_fp8(w[0], true);
        floatx2 f2 = __builtin_amdgcn_cvt_pk_f32_fp8(w[1], false);
        floatx2 f3 = __builtin_amdgcn_cvt_pk_f32_fp8(w[1], true);
        a0 += f0[0]; a1 += f0[1]; a2 += f1[0]; a3 += f1[1];
        a4 += f2[0]; a5 += f2[1]; a6 += f3[0]; a7 += f3[1];
    }
    const int ns = *nspill;             // 0 in practice
    if (ns > 0) {
        int lim = ns < SPILLMAX ? ns : SPILLMAX;
        for (int q = 0; q < lim; ++q) {
            if (spill[2 * q] == n) {
                int s = spill[2 * q + 1];
                u32x2 w = *(const u32x2*)(P1 + (long)s * 512 + l * 8);
                floatx2 f0 = __builtin_amdgcn_cvt_pk_f32_fp8(w[0], false);
                floatx2 f1 = __builtin_amdgcn_cvt_pk_f32_fp8(w[0], true);
                floatx2 f2 = __builtin_amdgcn_cvt_pk_f32_fp8(w[1], false);
                floatx2 f3 = __builtin_amdgcn_cvt_pk_f32_fp8(w[1], true);
                a0 += f0[0]; a1 += f0[1]; a2 += f1[0]; a3 += f1[1];
                a4 += f2[0]; a5 += f2[1]; a6 += f3[0]; a7 += f3[1];
            }
        }
    }
    float inv = 1.0f / (float)(c > 1 ? c : 1);
    us8 sf = *(const us8*)(C1s + (long)n * 512 + l * 8);
    us8 bv = *(const us8*)(b1c + l * 8);
    us8 o;
    o[0] = f2b(fmaxf(b2f(sf[0]) + a0 * inv + b2f(bv[0]), 0.f));
    o[1] = f2b(fmaxf(b2f(sf[1]) + a1 * inv + b2f(bv[1]), 0.f));
    o[2] = f2b(fmaxf(b2f(sf[2]) + a2 * inv + b2f(bv[2]), 0.f));
    o[3] = f2b(fmaxf(b2f(sf[3]) + a3 * inv + b2f(bv[3]), 0.f));
    o[4] = f2b(fmaxf(b2f(sf[4]) + a4 * inv + b2f(bv[4]), 0.f));
    o[5] = f2b(fmaxf(b2f(sf[5]) + a5 * inv + b2f(bv[5]), 0.f));
    o[6] = f2b(fmaxf(b2f(sf[6]) + a6 * inv + b2f(bv[6]), 0.f));
    o[7] = f2b(fmaxf(b2f(sf[7]) + a7 * inv + b2f(bv[7]), 0.f));
    *(us8*)(h1 + (long)n * 512 + l * 8) = o;
}

// ================= D5: out = C2s + mean(P2[nbrs]) + b2 ===========================
__global__ __launch_bounds__(256) void agg_out(const u16* __restrict__ P2,
                                               const u16* __restrict__ C2s,
                                               const u16* __restrict__ b2c,
                                               const int* __restrict__ cnt,
                                               const int* __restrict__ bucket,
                                               const int* __restrict__ nspill,
                                               const int* __restrict__ spill,
                                               void* __restrict__ outv, int Nn,
                                               const int* __restrict__ flags) {
    const int n = blockIdx.x * 4 + (threadIdx.x >> 6);
    const int l = threadIdx.x & 63;
    if (n >= Nn) return;
    const int c = cnt[n];
    const int inb = c < CAP ? c : CAP;
    const int* bk = bucket + (long)n * CAP;
    float a0 = 0.f, a1 = 0.f;
    int e = 0;
    for (; e + 3 < inb; e += 4) {
        int s0 = bk[e], s1 = bk[e + 1], s2 = bk[e + 2], s3 = bk[e + 3];
        us2 v0 = *(const us2*)(P2 + (long)s0 * 128 + l * 2);
        us2 v1 = *(const us2*)(P2 + (long)s1 * 128 + l * 2);
        us2 v2 = *(const us2*)(P2 + (long)s2 * 128 + l * 2);
        us2 v3 = *(const us2*)(P2 + (long)s3 * 128 + l * 2);
        a0 += (b2f(v0[0]) + b2f(v1[0])) + (b2f(v2[0]) + b2f(v3[0]));
        a1 += (b2f(v0[1]) + b2f(v1[1])) + (b2f(v2[1]) + b2f(v3[1]));
    }
    for (; e < inb; ++e) {
        int s0 = bk[e];
        us2 v0 = *(const us2*)(P2 + (long)s0 * 128 + l * 2);
        a0 += b2f(v0[0]); a1 += b2f(v0[1]);
    }
    const int ns = *nspill;
    if (ns > 0) {
        int lim = ns < SPILLMAX ? ns : SPILLMAX;
        for (int q = 0; q < lim; ++q) {
            if (spill[2 * q] == n) {
                int s0 = spill[2 * q + 1];
                us2 v0 = *(const us2*)(P2 + (long)s0 * 128 + l * 2);
                a0 += b2f(v0[0]); a1 += b2f(v0[1]);
            }
        }
    }
    float inv = 1.0f / (float)(c > 1 ? c : 1);
    us2 sf = *(const us2*)(C2s + (long)n * 128 + l * 2);
    us2 bv = *(const us2*)(b2c + l * 2);
    float o0 = b2f(sf[0]) + a0 * inv + b2f(bv[0]);
    float o1 = b2f(sf[1]) + a1 * inv + b2f(bv[1]);
    if (flags[0]) {
        float* o = (float*)outv + (long)n * 128 + l * 2;
        o[0] = o0; o[1] = o1;
    } else {
        us2 ob; ob[0] = f2b(o0); ob[1] = f2b(o1);
        *(us2*)((u16*)outv + (long)n * 128 + l * 2) = ob;
    }
}

// ================= launch ========================================================
extern "C" void kernel_launch(void* const* d_in, const int* in_sizes, int n_in,
                              void* d_out, int out_size, void* d_ws, size_t ws_size,
                              hipStream_t stream) {
    const int D = 512, NCLS = 128;
    const int Nn = in_sizes[0] / D;            // 10000
    const int E  = in_sizes[5];                // 160000
    const int mtiles = (Nn + 127) / 128;       // 79
    const int Mpad = mtiles * 128;             // 10112
    const int nFill = (E + 255) / 256;         // 625
    const int nHb = (Nn * D / 8 + 255) / 256;  // 2500

    const int* src = (const int*)d_in[5];
    const int* dst = (const int*)d_in[6];

    char* p = (char*)d_ws;
    u16* Hb  = (u16*)p; p += (size_t)Mpad * D * 2;
    u16* h1  = (u16*)p; p += (size_t)Mpad * D * 2;
    u16* C1s = (u16*)p; p += (size_t)Mpad * D * 2;
    u8*  P1  = (u8*)p;  p += (size_t)Mpad * D;        // fp8 e4m3
    u16* C2s = (u16*)p; p += (size_t)Mpad * NCLS * 2;
    u16* P2  = (u16*)p; p += (size_t)Mpad * NCLS * 2;
    u16* W1T = (u16*)p; p += (size_t)1024 * D * 2;
    u16* W2T = (u16*)p; p += (size_t)256 * D * 2;
    u16* b1c = (u16*)p; p += 1024;
    u16* b2c = (u16*)p; p += 1024;
    int* flags  = (int*)p; p += 256;
    int* cnt    = (int*)p; p += (size_t)(Nn + 60) * 4;
    int* nspill = cnt + Nn;
    int* bucket = (int*)p; p += (size_t)Nn * CAP * 4;
    int* spill  = (int*)p; p += (size_t)SPILLMAX * 2 * 4;

    hipMemsetAsync(cnt, 0, (size_t)(Nn + 60) * 4, stream);

    // D1: buckets + all conversions
    k_d1<<<nFill + nHb + 641, 256, 0, stream>>>(
        src, dst, E, Nn, cnt, bucket, nspill, spill,
        d_in[0], d_in[1], d_in[2], d_in[3], d_in[4],
        Hb, W1T, W2T, b1c, b2c, flags, nFill, nHb);

    // D2: [C1s(bf16) | P1(fp8)] = Hb @ W1T^T
    k_gemm1<<<dim3(mtiles, 8), 256, 0, stream>>>(Hb, W1T, C1s, P1, Nn);

    // D3: h1 = relu(C1s + mean(P1[nbrs]) + b1)  [wave-per-node]
    agg_h1<<<(Nn + 3) / 4, 256, 0, stream>>>(P1, C1s, b1c, cnt, bucket,
                                             nspill, spill, h1, Nn);

    // D4: [C2s|P2] = h1 @ W2T^T
    k_gemm2<<<dim3(mtiles, 2), 256, 0, stream>>>(h1, W2T, C2s, P2, Nn);

    // D5: out = C2s + mean(P2[nbrs]) + b2
    agg_out<<<(Nn + 3) / 4, 256, 0, stream>>>(P2, C2s, b2c, cnt, bucket,
                                              nspill, spill, d_out, Nn, flags);
}

// Round 9
// 160.146 us; speedup vs baseline: 1.0204x; 1.0143x over previous
//
#include <hip/hip_runtime.h>

typedef unsigned short u16;
typedef unsigned char u8;
typedef __attribute__((ext_vector_type(2))) float floatx2;
typedef __attribute__((ext_vector_type(4))) float floatx4;
typedef __attribute__((ext_vector_type(8))) __bf16 bf16x8;
typedef __attribute__((ext_vector_type(2))) unsigned short us2;
typedef __attribute__((ext_vector_type(4))) unsigned short us4;
typedef __attribute__((ext_vector_type(8))) unsigned short us8;
typedef __attribute__((ext_vector_type(2))) unsigned int u32x2;

static __device__ __forceinline__ float b2f(u16 v) {
    union { unsigned u; float f; } x; x.u = ((unsigned)v) << 16; return x.f;
}
static __device__ __forceinline__ u16 f2b(float f) {
    union { float f; unsigned u; } x; x.f = f;
    unsigned u = x.u;
    return (u16)((u + 0x7fffu + ((u >> 16) & 1u)) >> 16);
}

#define GLOAD_LDS16(g, l) __builtin_amdgcn_global_load_lds( \
    (const __attribute__((address_space(1))) void*)(g),     \
    (__attribute__((address_space(3))) void*)(l), 16, 0, 0)

#define CAP 64
#define SPILLMAX 4096

// Per-block dtype self-detection (see R5 notes): P(misdetect fp32) ~ 1e-65.
static __device__ __forceinline__ int detect_blk(const u16* __restrict__ p,
                                                 int nelem, int* sh) {
    if (threadIdx.x == 0) *sh = 0;
    __syncthreads();
    const int lim = nelem < 512 ? nelem : 512;
    int found = 0;
    for (int j = threadIdx.x; 2 * j < lim; j += 256) {
        unsigned v = p[2 * j] & 0x7fffu;
        if (v >= 0x4280u) found = 1;  // |bf16(bits)| >= 64.0
    }
    if (found) atomicOr(sh, 1);
    __syncthreads();
    return *sh;
}

// ================= D1: buckets + all conversions (self-detecting) ================
__global__ __launch_bounds__(256) void k_d1(
    const int* __restrict__ src, const int* __restrict__ dst, int E, int Nn,
    int* __restrict__ cnt, int* __restrict__ bucket,
    int* __restrict__ nspill, int* __restrict__ spill,
    const void* __restrict__ h, const void* __restrict__ W1,
    const void* __restrict__ b1, const void* __restrict__ W2,
    const void* __restrict__ b2,
    u16* __restrict__ Hb, u16* __restrict__ W1T, u16* __restrict__ W2T,
    u16* __restrict__ b1c, u16* __restrict__ b2c, int* __restrict__ flags,
    int nFill, int nHb) {
    __shared__ u16 tile[32][33];
    __shared__ int sh;
    const int b = blockIdx.x;
    const int t = threadIdx.x;

    if (b < nFill) {  // -------- bucket fill --------
        int e = b * 256 + t;
        if (e < E) {
            int d = dst[e], s = src[e];
            if ((unsigned)d < (unsigned)Nn && (unsigned)s < (unsigned)Nn) {
                int p = atomicAdd(&cnt[d], 1);
                if (p < CAP) bucket[d * CAP + p] = s;
                else {
                    int q = atomicAdd(nspill, 1);
                    if (q < SPILLMAX) { spill[2 * q] = d; spill[2 * q + 1] = s; }
                }
            }
        }
        return;
    }
    if (b < nFill + nHb) {  // -------- Hb cvt --------
        const int f = detect_blk((const u16*)h, Nn * 512, &sh);
        int i = ((b - nFill) * 256 + t) * 8;
        if (i >= Nn * 512) return;
        if (f) {
            const float* s = (const float*)h;
            us8 o;
#pragma unroll
            for (int k = 0; k < 8; ++k) o[k] = f2b(s[i + k]);
            *(us8*)(Hb + i) = o;
        } else {
            *(us8*)(Hb + i) = *(const us8*)((const u16*)h + i);
        }
        return;
    }
    if (b < nFill + nHb + 512) {  // -------- W1 [1024,512] -> W1T [1024,512] --------
        const int f = detect_blk((const u16*)W1, 1024 * 512, &sh);
        int sub = b - nFill - nHb;
        int half = sub >> 8, idx = sub & 255;
        const int bx = (idx & 15) * 32, by = (idx >> 4) * 32;
        const int koff = half * 512, noff = half * 512;
        const int tx = t & 31, ty = t >> 5;
        for (int i = ty; i < 32; i += 8) {
            long id = (long)(koff + by + i) * 512 + (bx + tx);
            tile[i][tx] = f ? f2b(((const float*)W1)[id]) : ((const u16*)W1)[id];
        }
        __syncthreads();
        for (int i = ty; i < 32; i += 8)
            W1T[(long)(noff + bx + i) * 512 + (by + tx)] = tile[tx][i];
        return;
    }
    if (b < nFill + nHb + 640) {  // -------- W2 [1024,128] -> W2T [256,512] --------
        const int f = detect_blk((const u16*)W2, 1024 * 128, &sh);
        int sub = b - nFill - nHb - 512;
        int half = sub >> 6, idx = sub & 63;
        const int bx = (idx & 3) * 32, by = (idx >> 2) * 32;
        const int koff = half * 512, noff = half * 128;
        const int tx = t & 31, ty = t >> 5;
        for (int i = ty; i < 32; i += 8) {
            long id = (long)(koff + by + i) * 128 + (bx + tx);
            tile[i][tx] = f ? f2b(((const float*)W2)[id]) : ((const u16*)W2)[id];
        }
        __syncthreads();
        for (int i = ty; i < 32; i += 8)
            W2T[(long)(noff + bx + i) * 512 + (by + tx)] = tile[tx][i];
        return;
    }
    // -------- biases + out-dtype flag --------
    {
        const int f1 = detect_blk((const u16*)b1, 512, &sh);
        for (int i = t; i < 512; i += 256)
            b1c[i] = f1 ? f2b(((const float*)b1)[i]) : ((const u16*)b1)[i];
        const int f2 = detect_blk((const u16*)b2, 128, &sh);
        if (t < 128)
            b2c[t] = f2 ? f2b(((const float*)b2)[t]) : ((const u16*)b2)[t];
        const int fh = detect_blk((const u16*)h, Nn * 512, &sh);
        if (t == 0) flags[0] = fh;
    }
}

// ================= GEMM accumulate core 128x128 (device) =========================
__device__ __forceinline__ void gemm_acc(const u16* __restrict__ A,
                                         const u16* __restrict__ Bt,
                                         long brow, int bcol,
                                         floatx4 acc[4][4], u16* lA, u16* lB) {
    const int tid = threadIdx.x;
    const int wv = tid >> 6;
    const int ln = tid & 63;
    const int wr = (wv >> 1) * 64;
    const int wc = (wv & 1) * 64;
    const int lrow = ln >> 2;
    const int lk = (ln & 3) * 8;
    const int m0 = ln & 15;
    const int kq = (ln >> 4) * 8;

#pragma unroll
    for (int i = 0; i < 4; ++i)
#pragma unroll
        for (int j = 0; j < 4; ++j) acc[i][j] = (floatx4){0.f, 0.f, 0.f, 0.f};

    for (int kt = 0; kt < 512; kt += 32) {
#pragma unroll
        for (int i = 0; i < 2; ++i) {
            const int c = i * 4 + wv;
            const int row = c * 16 + lrow;
            GLOAD_LDS16(A + (brow + row) * 512 + kt + lk, lA + c * 512);
            GLOAD_LDS16(Bt + (long)(bcol + row) * 512 + kt + lk, lB + c * 512);
        }
        __syncthreads();
        bf16x8 af[4], bf[4];
#pragma unroll
        for (int i = 0; i < 4; ++i)
            af[i] = *(const bf16x8*)(lA + (wr + i * 16 + m0) * 32 + kq);
#pragma unroll
        for (int j = 0; j < 4; ++j)
            bf[j] = *(const bf16x8*)(lB + (wc + j * 16 + m0) * 32 + kq);
#pragma unroll
        for (int i = 0; i < 4; ++i)
#pragma unroll
            for (int j = 0; j < 4; ++j)
                acc[i][j] = __builtin_amdgcn_mfma_f32_16x16x32_bf16(af[i], bf[j],
                                                                    acc[i][j], 0, 0, 0);
        __syncthreads();
    }
}

// ================= D2: GEMM1 ([C1s(bf16) | P1(fp8)] = Hb @ W1T^T) ================
__global__ __launch_bounds__(256) void k_gemm1(
    const u16* __restrict__ A, const u16* __restrict__ Bt,
    u16* __restrict__ C1s, u8* __restrict__ P1, int Mstore) {
    __shared__ __align__(16) u16 lA[128 * 32];
    __shared__ __align__(16) u16 lB[128 * 32];
    const int by = blockIdx.y;          // 0..7
    const int bcol = by * 128;
    const long brow = (long)blockIdx.x * 128;
    floatx4 acc[4][4];
    gemm_acc(A, Bt, brow, bcol, acc, lA, lB);

    const int ln = threadIdx.x & 63;
    const int wv = threadIdx.x >> 6;
    const int wr = (wv >> 1) * 64;
    const int wc = (wv & 1) * 64;
    const int m0 = ln & 15;
    const int q4 = (ln >> 4) * 4;
    if (by < 4) {  // self half -> bf16, ld 512
#pragma unroll
        for (int i = 0; i < 4; ++i)
#pragma unroll
            for (int r = 0; r < 4; ++r) {
                long row = brow + wr + i * 16 + q4 + r;
                if (row < Mstore) {
#pragma unroll
                    for (int j = 0; j < 4; ++j)
                        C1s[row * 512 + (bcol + wc + j * 16 + m0)] = f2b(acc[i][j][r]);
                }
            }
    } else {       // agg half -> fp8 e4m3 bytes, ld 512
        const int coff = bcol - 512;
#pragma unroll
        for (int i = 0; i < 4; ++i)
#pragma unroll
            for (int r = 0; r < 4; ++r) {
                long row = brow + wr + i * 16 + q4 + r;
                if (row < Mstore) {
#pragma unroll
                    for (int j = 0; j < 4; ++j) {
                        float v = acc[i][j][r];
                        int pk = __builtin_amdgcn_cvt_pk_fp8_f32(v, v, 0, false);
                        P1[row * 512 + (coff + wc + j * 16 + m0)] = (u8)(pk & 0xff);
                    }
                }
            }
    }
}

// ================= D4: GEMM2, 64x128 tiles for occupancy =========================
// grid (ceil(M/64), 2): by=0 -> C2s (Bt rows 0..127), by=1 -> P2 (Bt rows 128..255)
// 4 waves split N: wave wv covers cols wv*32..+32 (acc 4x2). LDS 12KB.
__global__ __launch_bounds__(256) void k_gemm2_64(
    const u16* __restrict__ A, const u16* __restrict__ Bt,
    u16* __restrict__ C2s, u16* __restrict__ P2, int Mstore) {
    __shared__ __align__(16) u16 lA[64 * 32];
    __shared__ __align__(16) u16 lB[128 * 32];
    const int tid = threadIdx.x;
    const int wv = tid >> 6;
    const int ln = tid & 63;
    const long brow = (long)blockIdx.x * 64;
    const int bobs = blockIdx.y * 128;   // Bt row offset
    const int lrow = ln >> 2;
    const int lk = (ln & 3) * 8;
    const int m0 = ln & 15;
    const int kq = (ln >> 4) * 8;
    const int wc = wv * 32;

    floatx4 acc[4][2];
#pragma unroll
    for (int i = 0; i < 4; ++i)
#pragma unroll
        for (int j = 0; j < 2; ++j) acc[i][j] = (floatx4){0.f, 0.f, 0.f, 0.f};

    for (int kt = 0; kt < 512; kt += 32) {
        // A: 4 chunks of 16 rows; wave wv stages chunk wv
        GLOAD_LDS16(A + (brow + wv * 16 + lrow) * 512 + kt + lk, lA + wv * 512);
        // B: 8 chunks; wave wv stages chunks wv and wv+4
#pragma unroll
        for (int i = 0; i < 2; ++i) {
            const int c = i * 4 + wv;
            GLOAD_LDS16(Bt + (long)(bobs + c * 16 + lrow) * 512 + kt + lk, lB + c * 512);
        }
        __syncthreads();
        bf16x8 af[4], bf[2];
#pragma unroll
        for (int i = 0; i < 4; ++i)
            af[i] = *(const bf16x8*)(lA + (i * 16 + m0) * 32 + kq);
#pragma unroll
        for (int j = 0; j < 2; ++j)
            bf[j] = *(const bf16x8*)(lB + (wc + j * 16 + m0) * 32 + kq);
#pragma unroll
        for (int i = 0; i < 4; ++i)
#pragma unroll
            for (int j = 0; j < 2; ++j)
                acc[i][j] = __builtin_amdgcn_mfma_f32_16x16x32_bf16(af[i], bf[j],
                                                                    acc[i][j], 0, 0, 0);
        __syncthreads();
    }

    u16* C = blockIdx.y ? P2 : C2s;
    const int q4 = (ln >> 4) * 4;
#pragma unroll
    for (int i = 0; i < 4; ++i)
#pragma unroll
        for (int r = 0; r < 4; ++r) {
            long row = brow + i * 16 + q4 + r;
            if (row < Mstore) {
#pragma unroll
                for (int j = 0; j < 2; ++j)
                    C[row * 128 + (wc + j * 16 + m0)] = f2b(acc[i][j][r]);
            }
        }
}

// ================= D3: h1 = relu(C1s + mean(P1fp8[nbrs]) + b1) ===================
// wave-per-node: one dwordx2 per edge; 8-deep gather unroll
__global__ __launch_bounds__(256) void agg_h1(const u8* __restrict__ P1,
                                              const u16* __restrict__ C1s,
                                              const u16* __restrict__ b1c,
                                              const int* __restrict__ cnt,
                                              const int* __restrict__ bucket,
                                              const int* __restrict__ nspill,
                                              const int* __restrict__ spill,
                                              u16* __restrict__ h1, int Nn) {
    const int n = blockIdx.x * 4 + (threadIdx.x >> 6);
    const int l = threadIdx.x & 63;
    if (n >= Nn) return;
    const int c = cnt[n];
    const int inb = c < CAP ? c : CAP;
    const int* bk = bucket + (long)n * CAP;
    float a0 = 0.f, a1 = 0.f, a2 = 0.f, a3 = 0.f;
    float a4 = 0.f, a5 = 0.f, a6 = 0.f, a7 = 0.f;
    int e = 0;
    for (; e + 7 < inb; e += 8) {
        u32x2 w[8];
#pragma unroll
        for (int q = 0; q < 8; ++q) {
            int s = bk[e + q];
            w[q] = *(const u32x2*)(P1 + (long)s * 512 + l * 8);
        }
#pragma unroll
        for (int q = 0; q < 8; ++q) {
            floatx2 f0 = __builtin_amdgcn_cvt_pk_f32_fp8(w[q][0], false);
            floatx2 f1 = __builtin_amdgcn_cvt_pk_f32_fp8(w[q][0], true);
            floatx2 f2 = __builtin_amdgcn_cvt_pk_f32_fp8(w[q][1], false);
            floatx2 f3 = __builtin_amdgcn_cvt_pk_f32_fp8(w[q][1], true);
            a0 += f0[0]; a1 += f0[1]; a2 += f1[0]; a3 += f1[1];
            a4 += f2[0]; a5 += f2[1]; a6 += f3[0]; a7 += f3[1];
        }
    }
    for (; e < inb; ++e) {
        int s = bk[e];
        u32x2 w = *(const u32x2*)(P1 + (long)s * 512 + l * 8);
        floatx2 f0 = __builtin_amdgcn_cvt_pk_f32_fp8(w[0], false);
        floatx2 f1 = __builtin_amdgcn_cvt_pk_f32_fp8(w[0], true);
        floatx2 f2 = __builtin_amdgcn_cvt_pk_f32_fp8(w[1], false);
        floatx2 f3 = __builtin_amdgcn_cvt_pk_f32_fp8(w[1], true);
        a0 += f0[0]; a1 += f0[1]; a2 += f1[0]; a3 += f1[1];
        a4 += f2[0]; a5 += f2[1]; a6 += f3[0]; a7 += f3[1];
    }
    const int ns = *nspill;             // 0 in practice
    if (ns > 0) {
        int lim = ns < SPILLMAX ? ns : SPILLMAX;
        for (int q = 0; q < lim; ++q) {
            if (spill[2 * q] == n) {
                int s = spill[2 * q + 1];
                u32x2 w = *(const u32x2*)(P1 + (long)s * 512 + l * 8);
                floatx2 f0 = __builtin_amdgcn_cvt_pk_f32_fp8(w[0], false);
                floatx2 f1 = __builtin_amdgcn_cvt_pk_f32_fp8(w[0], true);
                floatx2 f2 = __builtin_amdgcn_cvt_pk_f32_fp8(w[1], false);
                floatx2 f3 = __builtin_amdgcn_cvt_pk_f32_fp8(w[1], true);
                a0 += f0[0]; a1 += f0[1]; a2 += f1[0]; a3 += f1[1];
                a4 += f2[0]; a5 += f2[1]; a6 += f3[0]; a7 += f3[1];
            }
        }
    }
    float inv = 1.0f / (float)(c > 1 ? c : 1);
    us8 sf = *(const us8*)(C1s + (long)n * 512 + l * 8);
    us8 bv = *(const us8*)(b1c + l * 8);
    us8 o;
    o[0] = f2b(fmaxf(b2f(sf[0]) + a0 * inv + b2f(bv[0]), 0.f));
    o[1] = f2b(fmaxf(b2f(sf[1]) + a1 * inv + b2f(bv[1]), 0.f));
    o[2] = f2b(fmaxf(b2f(sf[2]) + a2 * inv + b2f(bv[2]), 0.f));
    o[3] = f2b(fmaxf(b2f(sf[3]) + a3 * inv + b2f(bv[3]), 0.f));
    o[4] = f2b(fmaxf(b2f(sf[4]) + a4 * inv + b2f(bv[4]), 0.f));
    o[5] = f2b(fmaxf(b2f(sf[5]) + a5 * inv + b2f(bv[5]), 0.f));
    o[6] = f2b(fmaxf(b2f(sf[6]) + a6 * inv + b2f(bv[6]), 0.f));
    o[7] = f2b(fmaxf(b2f(sf[7]) + a7 * inv + b2f(bv[7]), 0.f));
    *(us8*)(h1 + (long)n * 512 + l * 8) = o;
}

// ================= D5: out = C2s + mean(P2[nbrs]) + b2 ===========================
__global__ __launch_bounds__(256) void agg_out(const u16* __restrict__ P2,
                                               const u16* __restrict__ C2s,
                                               const u16* __restrict__ b2c,
                                               const int* __restrict__ cnt,
                                               const int* __restrict__ bucket,
                                               const int* __restrict__ nspill,
                                               const int* __restrict__ spill,
                                               void* __restrict__ outv, int Nn,
                                               const int* __restrict__ flags) {
    const int n = blockIdx.x * 4 + (threadIdx.x >> 6);
    const int l = threadIdx.x & 63;
    if (n >= Nn) return;
    const int c = cnt[n];
    const int inb = c < CAP ? c : CAP;
    const int* bk = bucket + (long)n * CAP;
    float a0 = 0.f, a1 = 0.f;
    int e = 0;
    for (; e + 3 < inb; e += 4) {
        int s0 = bk[e], s1 = bk[e + 1], s2 = bk[e + 2], s3 = bk[e + 3];
        us2 v0 = *(const us2*)(P2 + (long)s0 * 128 + l * 2);
        us2 v1 = *(const us2*)(P2 + (long)s1 * 128 + l * 2);
        us2 v2 = *(const us2*)(P2 + (long)s2 * 128 + l * 2);
        us2 v3 = *(const us2*)(P2 + (long)s3 * 128 + l * 2);
        a0 += (b2f(v0[0]) + b2f(v1[0])) + (b2f(v2[0]) + b2f(v3[0]));
        a1 += (b2f(v0[1]) + b2f(v1[1])) + (b2f(v2[1]) + b2f(v3[1]));
    }
    for (; e < inb; ++e) {
        int s0 = bk[e];
        us2 v0 = *(const us2*)(P2 + (long)s0 * 128 + l * 2);
        a0 += b2f(v0[0]); a1 += b2f(v0[1]);
    }
    const int ns = *nspill;
    if (ns > 0) {
        int lim = ns < SPILLMAX ? ns : SPILLMAX;
        for (int q = 0; q < lim; ++q) {
            if (spill[2 * q] == n) {
                int s0 = spill[2 * q + 1];
                us2 v0 = *(const us2*)(P2 + (long)s0 * 128 + l * 2);
                a0 += b2f(v0[0]); a1 += b2f(v0[1]);
            }
        }
    }
    float inv = 1.0f / (float)(c > 1 ? c : 1);
    us2 sf = *(const us2*)(C2s + (long)n * 128 + l * 2);
    us2 bv = *(const us2*)(b2c + l * 2);
    float o0 = b2f(sf[0]) + a0 * inv + b2f(bv[0]);
    float o1 = b2f(sf[1]) + a1 * inv + b2f(bv[1]);
    if (flags[0]) {
        float* o = (float*)outv + (long)n * 128 + l * 2;
        o[0] = o0; o[1] = o1;
    } else {
        us2 ob; ob[0] = f2b(o0); ob[1] = f2b(o1);
        *(us2*)((u16*)outv + (long)n * 128 + l * 2) = ob;
    }
}

// ================= launch ========================================================
extern "C" void kernel_launch(void* const* d_in, const int* in_sizes, int n_in,
                              void* d_out, int out_size, void* d_ws, size_t ws_size,
                              hipStream_t stream) {
    const int D = 512, NCLS = 128;
    const int Nn = in_sizes[0] / D;            // 10000
    const int E  = in_sizes[5];                // 160000
    const int mtiles = (Nn + 127) / 128;       // 79
    const int mt64 = (Nn + 63) / 64;           // 157
    const int Mpad = mtiles * 128;             // 10112
    const int nFill = (E + 255) / 256;         // 625
    const int nHb = (Nn * D / 8 + 255) / 256;  // 2500

    const int* src = (const int*)d_in[5];
    const int* dst = (const int*)d_in[6];

    char* p = (char*)d_ws;
    u16* Hb  = (u16*)p; p += (size_t)Mpad * D * 2;
    u16* h1  = (u16*)p; p += (size_t)Mpad * D * 2;
    u16* C1s = (u16*)p; p += (size_t)Mpad * D * 2;
    u8*  P1  = (u8*)p;  p += (size_t)Mpad * D;        // fp8 e4m3
    u16* C2s = (u16*)p; p += (size_t)Mpad * NCLS * 2;
    u16* P2  = (u16*)p; p += (size_t)Mpad * NCLS * 2;
    u16* W1T = (u16*)p; p += (size_t)1024 * D * 2;
    u16* W2T = (u16*)p; p += (size_t)256 * D * 2;
    u16* b1c = (u16*)p; p += 1024;
    u16* b2c = (u16*)p; p += 1024;
    int* flags  = (int*)p; p += 256;
    int* cnt    = (int*)p; p += (size_t)(Nn + 60) * 4;
    int* nspill = cnt + Nn;
    int* bucket = (int*)p; p += (size_t)Nn * CAP * 4;
    int* spill  = (int*)p; p += (size_t)SPILLMAX * 2 * 4;

    hipMemsetAsync(cnt, 0, (size_t)(Nn + 60) * 4, stream);

    // D1: buckets + all conversions
    k_d1<<<nFill + nHb + 641, 256, 0, stream>>>(
        src, dst, E, Nn, cnt, bucket, nspill, spill,
        d_in[0], d_in[1], d_in[2], d_in[3], d_in[4],
        Hb, W1T, W2T, b1c, b2c, flags, nFill, nHb);

    // D2: [C1s(bf16) | P1(fp8)] = Hb @ W1T^T
    k_gemm1<<<dim3(mtiles, 8), 256, 0, stream>>>(Hb, W1T, C1s, P1, Nn);

    // D3: h1 = relu(C1s + mean(P1[nbrs]) + b1)  [wave-per-node]
    agg_h1<<<(Nn + 3) / 4, 256, 0, stream>>>(P1, C1s, b1c, cnt, bucket,
                                             nspill, spill, h1, Nn);

    // D4: [C2s|P2] = h1 @ W2T^T  [64x128 tiles, 314 blocks]
    k_gemm2_64<<<dim3(mt64, 2), 256, 0, stream>>>(h1, W2T, C2s, P2, Nn);

    // D5: out = C2s + mean(P2[nbrs]) + b2
    agg_out<<<(Nn + 3) / 4, 256, 0, stream>>>(P2, C2s, b2c, cnt, bucket,
                                              nspill, spill, d_out, Nn, flags);
}

// Round 10
// 157.895 us; speedup vs baseline: 1.0349x; 1.0143x over previous
//
#include <hip/hip_runtime.h>

typedef unsigned short u16;
typedef unsigned char u8;
typedef __attribute__((ext_vector_type(2))) float floatx2;
typedef __attribute__((ext_vector_type(4))) float floatx4;
typedef __attribute__((ext_vector_type(8))) __bf16 bf16x8;
typedef __attribute__((ext_vector_type(2))) unsigned short us2;
typedef __attribute__((ext_vector_type(4))) unsigned short us4;
typedef __attribute__((ext_vector_type(8))) unsigned short us8;
typedef __attribute__((ext_vector_type(2))) unsigned int u32x2;

static __device__ __forceinline__ float b2f(u16 v) {
    union { unsigned u; float f; } x; x.u = ((unsigned)v) << 16; return x.f;
}
static __device__ __forceinline__ u16 f2b(float f) {
    union { float f; unsigned u; } x; x.f = f;
    unsigned u = x.u;
    return (u16)((u + 0x7fffu + ((u >> 16) & 1u)) >> 16);
}

#define GLOAD_LDS16(g, l) __builtin_amdgcn_global_load_lds( \
    (const __attribute__((address_space(1))) void*)(g),     \
    (__attribute__((address_space(3))) void*)(l), 16, 0, 0)

#define CAP 64
#define SPILLMAX 4096

// Per-block dtype self-detection (see R5 notes): P(misdetect fp32) ~ 1e-65.
static __device__ __forceinline__ int detect_blk(const u16* __restrict__ p,
                                                 int nelem, int* sh) {
    if (threadIdx.x == 0) *sh = 0;
    __syncthreads();
    const int lim = nelem < 512 ? nelem : 512;
    int found = 0;
    for (int j = threadIdx.x; 2 * j < lim; j += 256) {
        unsigned v = p[2 * j] & 0x7fffu;
        if (v >= 0x4280u) found = 1;  // |bf16(bits)| >= 64.0
    }
    if (found) atomicOr(sh, 1);
    __syncthreads();
    return *sh;
}

// ================= D1: buckets + all conversions (self-detecting) ================
__global__ __launch_bounds__(256) void k_d1(
    const int* __restrict__ src, const int* __restrict__ dst, int E, int Nn,
    int* __restrict__ cnt, int* __restrict__ bucket,
    int* __restrict__ nspill, int* __restrict__ spill,
    const void* __restrict__ h, const void* __restrict__ W1,
    const void* __restrict__ b1, const void* __restrict__ W2,
    const void* __restrict__ b2,
    u16* __restrict__ Hb, u16* __restrict__ W1T, u16* __restrict__ W2T,
    u16* __restrict__ b1c, u16* __restrict__ b2c, int* __restrict__ flags,
    int nFill, int nHb) {
    __shared__ u16 tile[32][33];
    __shared__ int sh;
    const int b = blockIdx.x;
    const int t = threadIdx.x;

    if (b < nFill) {  // -------- bucket fill --------
        int e = b * 256 + t;
        if (e < E) {
            int d = dst[e], s = src[e];
            if ((unsigned)d < (unsigned)Nn && (unsigned)s < (unsigned)Nn) {
                int p = atomicAdd(&cnt[d], 1);
                if (p < CAP) bucket[d * CAP + p] = s;
                else {
                    int q = atomicAdd(nspill, 1);
                    if (q < SPILLMAX) { spill[2 * q] = d; spill[2 * q + 1] = s; }
                }
            }
        }
        return;
    }
    if (b < nFill + nHb) {  // -------- Hb cvt --------
        const int f = detect_blk((const u16*)h, Nn * 512, &sh);
        int i = ((b - nFill) * 256 + t) * 8;
        if (i >= Nn * 512) return;
        if (f) {
            const float* s = (const float*)h;
            us8 o;
#pragma unroll
            for (int k = 0; k < 8; ++k) o[k] = f2b(s[i + k]);
            *(us8*)(Hb + i) = o;
        } else {
            *(us8*)(Hb + i) = *(const us8*)((const u16*)h + i);
        }
        return;
    }
    if (b < nFill + nHb + 512) {  // -------- W1 [1024,512] -> W1T [1024,512] --------
        const int f = detect_blk((const u16*)W1, 1024 * 512, &sh);
        int sub = b - nFill - nHb;
        int half = sub >> 8, idx = sub & 255;
        const int bx = (idx & 15) * 32, by = (idx >> 4) * 32;
        const int koff = half * 512, noff = half * 512;
        const int tx = t & 31, ty = t >> 5;
        for (int i = ty; i < 32; i += 8) {
            long id = (long)(koff + by + i) * 512 + (bx + tx);
            tile[i][tx] = f ? f2b(((const float*)W1)[id]) : ((const u16*)W1)[id];
        }
        __syncthreads();
        for (int i = ty; i < 32; i += 8)
            W1T[(long)(noff + bx + i) * 512 + (by + tx)] = tile[tx][i];
        return;
    }
    if (b < nFill + nHb + 640) {  // -------- W2 [1024,128] -> W2T [256,512] --------
        const int f = detect_blk((const u16*)W2, 1024 * 128, &sh);
        int sub = b - nFill - nHb - 512;
        int half = sub >> 6, idx = sub & 63;
        const int bx = (idx & 3) * 32, by = (idx >> 2) * 32;
        const int koff = half * 512, noff = half * 128;
        const int tx = t & 31, ty = t >> 5;
        for (int i = ty; i < 32; i += 8) {
            long id = (long)(koff + by + i) * 128 + (bx + tx);
            tile[i][tx] = f ? f2b(((const float*)W2)[id]) : ((const u16*)W2)[id];
        }
        __syncthreads();
        for (int i = ty; i < 32; i += 8)
            W2T[(long)(noff + bx + i) * 512 + (by + tx)] = tile[tx][i];
        return;
    }
    // -------- biases + out-dtype flag --------
    {
        const int f1 = detect_blk((const u16*)b1, 512, &sh);
        for (int i = t; i < 512; i += 256)
            b1c[i] = f1 ? f2b(((const float*)b1)[i]) : ((const u16*)b1)[i];
        const int f2 = detect_blk((const u16*)b2, 128, &sh);
        if (t < 128)
            b2c[t] = f2 ? f2b(((const float*)b2)[t]) : ((const u16*)b2)[t];
        const int fh = detect_blk((const u16*)h, Nn * 512, &sh);
        if (t == 0) flags[0] = fh;
    }
}

// ================= 64x128 GEMM accumulate core (device) ==========================
// A tile 64 rows, B tile 128 rows (Bt row offset bobs). 4 waves split N:
// wave wv covers cols wv*32..+32, acc 4x2. LDS 12KB. Per-output K order is
// identical to the 128x128 core -> bit-identical results.
__device__ __forceinline__ void gemm_acc64(const u16* __restrict__ A,
                                           const u16* __restrict__ Bt,
                                           long brow, int bobs,
                                           floatx4 acc[4][2], u16* lA, u16* lB) {
    const int tid = threadIdx.x;
    const int wv = tid >> 6;
    const int ln = tid & 63;
    const int lrow = ln >> 2;
    const int lk = (ln & 3) * 8;
    const int m0 = ln & 15;
    const int kq = (ln >> 4) * 8;
    const int wc = wv * 32;

#pragma unroll
    for (int i = 0; i < 4; ++i)
#pragma unroll
        for (int j = 0; j < 2; ++j) acc[i][j] = (floatx4){0.f, 0.f, 0.f, 0.f};

    for (int kt = 0; kt < 512; kt += 32) {
        // A: 4 chunks of 16 rows; wave wv stages chunk wv
        GLOAD_LDS16(A + (brow + wv * 16 + lrow) * 512 + kt + lk, lA + wv * 512);
        // B: 8 chunks; wave wv stages chunks wv and wv+4
#pragma unroll
        for (int i = 0; i < 2; ++i) {
            const int c = i * 4 + wv;
            GLOAD_LDS16(Bt + (long)(bobs + c * 16 + lrow) * 512 + kt + lk, lB + c * 512);
        }
        __syncthreads();
        bf16x8 af[4], bf[2];
#pragma unroll
        for (int i = 0; i < 4; ++i)
            af[i] = *(const bf16x8*)(lA + (i * 16 + m0) * 32 + kq);
#pragma unroll
        for (int j = 0; j < 2; ++j)
            bf[j] = *(const bf16x8*)(lB + (wc + j * 16 + m0) * 32 + kq);
#pragma unroll
        for (int i = 0; i < 4; ++i)
#pragma unroll
            for (int j = 0; j < 2; ++j)
                acc[i][j] = __builtin_amdgcn_mfma_f32_16x16x32_bf16(af[i], bf[j],
                                                                    acc[i][j], 0, 0, 0);
        __syncthreads();
    }
}

// ================= D2: GEMM1 64x128 ([C1s(bf16) | P1(fp8)] = Hb @ W1T^T) =========
// grid (ceil(M/64), 8) = 1264 blocks (~4.9/CU)
__global__ __launch_bounds__(256) void k_gemm1_64(
    const u16* __restrict__ A, const u16* __restrict__ Bt,
    u16* __restrict__ C1s, u8* __restrict__ P1, int Mstore) {
    __shared__ __align__(16) u16 lA[64 * 32];
    __shared__ __align__(16) u16 lB[128 * 32];
    const int by = blockIdx.y;           // 0..7
    const int bcol = by * 128;
    const long brow = (long)blockIdx.x * 64;
    floatx4 acc[4][2];
    gemm_acc64(A, Bt, brow, bcol, acc, lA, lB);

    const int ln = threadIdx.x & 63;
    const int wv = threadIdx.x >> 6;
    const int wc = wv * 32;
    const int m0 = ln & 15;
    const int q4 = (ln >> 4) * 4;
    if (by < 4) {  // self half -> bf16, ld 512
#pragma unroll
        for (int i = 0; i < 4; ++i)
#pragma unroll
            for (int r = 0; r < 4; ++r) {
                long row = brow + i * 16 + q4 + r;
                if (row < Mstore) {
#pragma unroll
                    for (int j = 0; j < 2; ++j)
                        C1s[row * 512 + (bcol + wc + j * 16 + m0)] = f2b(acc[i][j][r]);
                }
            }
    } else {       // agg half -> fp8 e4m3 bytes, ld 512
        const int coff = bcol - 512;
#pragma unroll
        for (int i = 0; i < 4; ++i)
#pragma unroll
            for (int r = 0; r < 4; ++r) {
                long row = brow + i * 16 + q4 + r;
                if (row < Mstore) {
#pragma unroll
                    for (int j = 0; j < 2; ++j) {
                        float v = acc[i][j][r];
                        int pk = __builtin_amdgcn_cvt_pk_fp8_f32(v, v, 0, false);
                        P1[row * 512 + (coff + wc + j * 16 + m0)] = (u8)(pk & 0xff);
                    }
                }
            }
    }
}

// ================= D4: GEMM2 64x128 ([C2s|P2] = h1 @ W2T^T) ======================
__global__ __launch_bounds__(256) void k_gemm2_64(
    const u16* __restrict__ A, const u16* __restrict__ Bt,
    u16* __restrict__ C2s, u16* __restrict__ P2, int Mstore) {
    __shared__ __align__(16) u16 lA[64 * 32];
    __shared__ __align__(16) u16 lB[128 * 32];
    const long brow = (long)blockIdx.x * 64;
    floatx4 acc[4][2];
    gemm_acc64(A, Bt, brow, blockIdx.y * 128, acc, lA, lB);

    u16* C = blockIdx.y ? P2 : C2s;
    const int ln = threadIdx.x & 63;
    const int wv = threadIdx.x >> 6;
    const int wc = wv * 32;
    const int m0 = ln & 15;
    const int q4 = (ln >> 4) * 4;
#pragma unroll
    for (int i = 0; i < 4; ++i)
#pragma unroll
        for (int r = 0; r < 4; ++r) {
            long row = brow + i * 16 + q4 + r;
            if (row < Mstore) {
#pragma unroll
                for (int j = 0; j < 2; ++j)
                    C[row * 128 + (wc + j * 16 + m0)] = f2b(acc[i][j][r]);
            }
        }
}

// ================= D3: h1 = relu(C1s + mean(P1fp8[nbrs]) + b1) ===================
// wave-per-node: one dwordx2 per edge; 8-deep gather unroll
__global__ __launch_bounds__(256) void agg_h1(const u8* __restrict__ P1,
                                              const u16* __restrict__ C1s,
                                              const u16* __restrict__ b1c,
                                              const int* __restrict__ cnt,
                                              const int* __restrict__ bucket,
                                              const int* __restrict__ nspill,
                                              const int* __restrict__ spill,
                                              u16* __restrict__ h1, int Nn) {
    const int n = blockIdx.x * 4 + (threadIdx.x >> 6);
    const int l = threadIdx.x & 63;
    if (n >= Nn) return;
    const int c = cnt[n];
    const int inb = c < CAP ? c : CAP;
    const int* bk = bucket + (long)n * CAP;
    float a0 = 0.f, a1 = 0.f, a2 = 0.f, a3 = 0.f;
    float a4 = 0.f, a5 = 0.f, a6 = 0.f, a7 = 0.f;
    int e = 0;
    for (; e + 7 < inb; e += 8) {
        u32x2 w[8];
#pragma unroll
        for (int q = 0; q < 8; ++q) {
            int s = bk[e + q];
            w[q] = *(const u32x2*)(P1 + (long)s * 512 + l * 8);
        }
#pragma unroll
        for (int q = 0; q < 8; ++q) {
            floatx2 f0 = __builtin_amdgcn_cvt_pk_f32_fp8(w[q][0], false);
            floatx2 f1 = __builtin_amdgcn_cvt_pk_f32_fp8(w[q][0], true);
            floatx2 f2 = __builtin_amdgcn_cvt_pk_f32_fp8(w[q][1], false);
            floatx2 f3 = __builtin_amdgcn_cvt_pk_f32_fp8(w[q][1], true);
            a0 += f0[0]; a1 += f0[1]; a2 += f1[0]; a3 += f1[1];
            a4 += f2[0]; a5 += f2[1]; a6 += f3[0]; a7 += f3[1];
        }
    }
    for (; e < inb; ++e) {
        int s = bk[e];
        u32x2 w = *(const u32x2*)(P1 + (long)s * 512 + l * 8);
        floatx2 f0 = __builtin_amdgcn_cvt_pk_f32_fp8(w[0], false);
        floatx2 f1 = __builtin_amdgcn_cvt_pk_f32_fp8(w[0], true);
        floatx2 f2 = __builtin_amdgcn_cvt_pk_f32_fp8(w[1], false);
        floatx2 f3 = __builtin_amdgcn_cvt_pk_f32_fp8(w[1], true);
        a0 += f0[0]; a1 += f0[1]; a2 += f1[0]; a3 += f1[1];
        a4 += f2[0]; a5 += f2[1]; a6 += f3[0]; a7 += f3[1];
    }
    const int ns = *nspill;             // 0 in practice
    if (ns > 0) {
        int lim = ns < SPILLMAX ? ns : SPILLMAX;
        for (int q = 0; q < lim; ++q) {
            if (spill[2 * q] == n) {
                int s = spill[2 * q + 1];
                u32x2 w = *(const u32x2*)(P1 + (long)s * 512 + l * 8);
                floatx2 f0 = __builtin_amdgcn_cvt_pk_f32_fp8(w[0], false);
                floatx2 f1 = __builtin_amdgcn_cvt_pk_f32_fp8(w[0], true);
                floatx2 f2 = __builtin_amdgcn_cvt_pk_f32_fp8(w[1], false);
                floatx2 f3 = __builtin_amdgcn_cvt_pk_f32_fp8(w[1], true);
                a0 += f0[0]; a1 += f0[1]; a2 += f1[0]; a3 += f1[1];
                a4 += f2[0]; a5 += f2[1]; a6 += f3[0]; a7 += f3[1];
            }
        }
    }
    float inv = 1.0f / (float)(c > 1 ? c : 1);
    us8 sf = *(const us8*)(C1s + (long)n * 512 + l * 8);
    us8 bv = *(const us8*)(b1c + l * 8);
    us8 o;
    o[0] = f2b(fmaxf(b2f(sf[0]) + a0 * inv + b2f(bv[0]), 0.f));
    o[1] = f2b(fmaxf(b2f(sf[1]) + a1 * inv + b2f(bv[1]), 0.f));
    o[2] = f2b(fmaxf(b2f(sf[2]) + a2 * inv + b2f(bv[2]), 0.f));
    o[3] = f2b(fmaxf(b2f(sf[3]) + a3 * inv + b2f(bv[3]), 0.f));
    o[4] = f2b(fmaxf(b2f(sf[4]) + a4 * inv + b2f(bv[4]), 0.f));
    o[5] = f2b(fmaxf(b2f(sf[5]) + a5 * inv + b2f(bv[5]), 0.f));
    o[6] = f2b(fmaxf(b2f(sf[6]) + a6 * inv + b2f(bv[6]), 0.f));
    o[7] = f2b(fmaxf(b2f(sf[7]) + a7 * inv + b2f(bv[7]), 0.f));
    *(us8*)(h1 + (long)n * 512 + l * 8) = o;
}

// ================= D5: out = C2s + mean(P2[nbrs]) + b2 ===========================
__global__ __launch_bounds__(256) void agg_out(const u16* __restrict__ P2,
                                               const u16* __restrict__ C2s,
                                               const u16* __restrict__ b2c,
                                               const int* __restrict__ cnt,
                                               const int* __restrict__ bucket,
                                               const int* __restrict__ nspill,
                                               const int* __restrict__ spill,
                                               void* __restrict__ outv, int Nn,
                                               const int* __restrict__ flags) {
    const int n = blockIdx.x * 4 + (threadIdx.x >> 6);
    const int l = threadIdx.x & 63;
    if (n >= Nn) return;
    const int c = cnt[n];
    const int inb = c < CAP ? c : CAP;
    const int* bk = bucket + (long)n * CAP;
    float a0 = 0.f, a1 = 0.f;
    int e = 0;
    for (; e + 3 < inb; e += 4) {
        int s0 = bk[e], s1 = bk[e + 1], s2 = bk[e + 2], s3 = bk[e + 3];
        us2 v0 = *(const us2*)(P2 + (long)s0 * 128 + l * 2);
        us2 v1 = *(const us2*)(P2 + (long)s1 * 128 + l * 2);
        us2 v2 = *(const us2*)(P2 + (long)s2 * 128 + l * 2);
        us2 v3 = *(const us2*)(P2 + (long)s3 * 128 + l * 2);
        a0 += (b2f(v0[0]) + b2f(v1[0])) + (b2f(v2[0]) + b2f(v3[0]));
        a1 += (b2f(v0[1]) + b2f(v1[1])) + (b2f(v2[1]) + b2f(v3[1]));
    }
    for (; e < inb; ++e) {
        int s0 = bk[e];
        us2 v0 = *(const us2*)(P2 + (long)s0 * 128 + l * 2);
        a0 += b2f(v0[0]); a1 += b2f(v0[1]);
    }
    const int ns = *nspill;
    if (ns > 0) {
        int lim = ns < SPILLMAX ? ns : SPILLMAX;
        for (int q = 0; q < lim; ++q) {
            if (spill[2 * q] == n) {
                int s0 = spill[2 * q + 1];
                us2 v0 = *(const us2*)(P2 + (long)s0 * 128 + l * 2);
                a0 += b2f(v0[0]); a1 += b2f(v0[1]);
            }
        }
    }
    float inv = 1.0f / (float)(c > 1 ? c : 1);
    us2 sf = *(const us2*)(C2s + (long)n * 128 + l * 2);
    us2 bv = *(const us2*)(b2c + l * 2);
    float o0 = b2f(sf[0]) + a0 * inv + b2f(bv[0]);
    float o1 = b2f(sf[1]) + a1 * inv + b2f(bv[1]);
    if (flags[0]) {
        float* o = (float*)outv + (long)n * 128 + l * 2;
        o[0] = o0; o[1] = o1;
    } else {
        us2 ob; ob[0] = f2b(o0); ob[1] = f2b(o1);
        *(us2*)((u16*)outv + (long)n * 128 + l * 2) = ob;
    }
}

// ================= launch ========================================================
extern "C" void kernel_launch(void* const* d_in, const int* in_sizes, int n_in,
                              void* d_out, int out_size, void* d_ws, size_t ws_size,
                              hipStream_t stream) {
    const int D = 512, NCLS = 128;
    const int Nn = in_sizes[0] / D;            // 10000
    const int E  = in_sizes[5];                // 160000
    const int mtiles = (Nn + 127) / 128;       // 79
    const int mt64 = (Nn + 63) / 64;           // 157
    const int Mpad = mtiles * 128;             // 10112
    const int nFill = (E + 255) / 256;         // 625
    const int nHb = (Nn * D / 8 + 255) / 256;  // 2500

    const int* src = (const int*)d_in[5];
    const int* dst = (const int*)d_in[6];

    char* p = (char*)d_ws;
    u16* Hb  = (u16*)p; p += (size_t)Mpad * D * 2;
    u16* h1  = (u16*)p; p += (size_t)Mpad * D * 2;
    u16* C1s = (u16*)p; p += (size_t)Mpad * D * 2;
    u8*  P1  = (u8*)p;  p += (size_t)Mpad * D;        // fp8 e4m3
    u16* C2s = (u16*)p; p += (size_t)Mpad * NCLS * 2;
    u16* P2  = (u16*)p; p += (size_t)Mpad * NCLS * 2;
    u16* W1T = (u16*)p; p += (size_t)1024 * D * 2;
    u16* W2T = (u16*)p; p += (size_t)256 * D * 2;
    u16* b1c = (u16*)p; p += 1024;
    u16* b2c = (u16*)p; p += 1024;
    int* flags  = (int*)p; p += 256;
    int* cnt    = (int*)p; p += (size_t)(Nn + 60) * 4;
    int* nspill = cnt + Nn;
    int* bucket = (int*)p; p += (size_t)Nn * CAP * 4;
    int* spill  = (int*)p; p += (size_t)SPILLMAX * 2 * 4;

    hipMemsetAsync(cnt, 0, (size_t)(Nn + 60) * 4, stream);

    // D1: buckets + all conversions
    k_d1<<<nFill + nHb + 641, 256, 0, stream>>>(
        src, dst, E, Nn, cnt, bucket, nspill, spill,
        d_in[0], d_in[1], d_in[2], d_in[3], d_in[4],
        Hb, W1T, W2T, b1c, b2c, flags, nFill, nHb);

    // D2: [C1s(bf16) | P1(fp8)] = Hb @ W1T^T  [64x128 tiles, 1264 blocks]
    k_gemm1_64<<<dim3(mt64, 8), 256, 0, stream>>>(Hb, W1T, C1s, P1, Nn);

    // D3: h1 = relu(C1s + mean(P1[nbrs]) + b1)  [wave-per-node]
    agg_h1<<<(Nn + 3) / 4, 256, 0, stream>>>(P1, C1s, b1c, cnt, bucket,
                                             nspill, spill, h1, Nn);

    // D4: [C2s|P2] = h1 @ W2T^T  [64x128 tiles, 314 blocks]
    k_gemm2_64<<<dim3(mt64, 2), 256, 0, stream>>>(h1, W2T, C2s, P2, Nn);

    // D5: out = C2s + mean(P2[nbrs]) + b2
    agg_out<<<(Nn + 3) / 4, 256, 0, stream>>>(P2, C2s, b2c, cnt, bucket,
                                              nspill, spill, d_out, Nn, flags);
}

// Round 11
// 157.828 us; speedup vs baseline: 1.0353x; 1.0004x over previous
//
#include <hip/hip_runtime.h>

typedef unsigned short u16;
typedef unsigned char u8;
typedef __attribute__((ext_vector_type(2))) float floatx2;
typedef __attribute__((ext_vector_type(4))) float floatx4;
typedef __attribute__((ext_vector_type(8))) __bf16 bf16x8;
typedef __attribute__((ext_vector_type(2))) unsigned short us2;
typedef __attribute__((ext_vector_type(4))) unsigned short us4;
typedef __attribute__((ext_vector_type(8))) unsigned short us8;
typedef __attribute__((ext_vector_type(2))) unsigned int u32x2;

static __device__ __forceinline__ float b2f(u16 v) {
    union { unsigned u; float f; } x; x.u = ((unsigned)v) << 16; return x.f;
}
static __device__ __forceinline__ u16 f2b(float f) {
    union { float f; unsigned u; } x; x.f = f;
    unsigned u = x.u;
    return (u16)((u + 0x7fffu + ((u >> 16) & 1u)) >> 16);
}

#define GLOAD_LDS16(g, l) __builtin_amdgcn_global_load_lds( \
    (const __attribute__((address_space(1))) void*)(g),     \
    (__attribute__((address_space(3))) void*)(l), 16, 0, 0)

#define CAP 64
#define SPILLMAX 4096

// Per-block dtype self-detection (see R5 notes): P(misdetect fp32) ~ 1e-65.
static __device__ __forceinline__ int detect_blk(const u16* __restrict__ p,
                                                 int nelem, int* sh) {
    if (threadIdx.x == 0) *sh = 0;
    __syncthreads();
    const int lim = nelem < 512 ? nelem : 512;
    int found = 0;
    for (int j = threadIdx.x; 2 * j < lim; j += 256) {
        unsigned v = p[2 * j] & 0x7fffu;
        if (v >= 0x4280u) found = 1;  // |bf16(bits)| >= 64.0
    }
    if (found) atomicOr(sh, 1);
    __syncthreads();
    return *sh;
}

// ================= D1: buckets + all conversions (self-detecting) ================
__global__ __launch_bounds__(256) void k_d1(
    const int* __restrict__ src, const int* __restrict__ dst, int E, int Nn,
    int* __restrict__ cnt, int* __restrict__ bucket,
    int* __restrict__ nspill, int* __restrict__ spill,
    const void* __restrict__ h, const void* __restrict__ W1,
    const void* __restrict__ b1, const void* __restrict__ W2,
    const void* __restrict__ b2,
    u16* __restrict__ Hb, u16* __restrict__ W1T, u16* __restrict__ W2T,
    u16* __restrict__ b1c, u16* __restrict__ b2c, int* __restrict__ flags,
    int nFill, int nHb) {
    __shared__ u16 tile[32][33];
    __shared__ int sh;
    const int b = blockIdx.x;
    const int t = threadIdx.x;

    if (b < nFill) {  // -------- bucket fill --------
        int e = b * 256 + t;
        if (e < E) {
            int d = dst[e], s = src[e];
            if ((unsigned)d < (unsigned)Nn && (unsigned)s < (unsigned)Nn) {
                int p = atomicAdd(&cnt[d], 1);
                if (p < CAP) bucket[d * CAP + p] = s;
                else {
                    int q = atomicAdd(nspill, 1);
                    if (q < SPILLMAX) { spill[2 * q] = d; spill[2 * q + 1] = s; }
                }
            }
        }
        return;
    }
    if (b < nFill + nHb) {  // -------- Hb cvt --------
        const int f = detect_blk((const u16*)h, Nn * 512, &sh);
        int i = ((b - nFill) * 256 + t) * 8;
        if (i >= Nn * 512) return;
        if (f) {
            const float* s = (const float*)h;
            us8 o;
#pragma unroll
            for (int k = 0; k < 8; ++k) o[k] = f2b(s[i + k]);
            *(us8*)(Hb + i) = o;
        } else {
            *(us8*)(Hb + i) = *(const us8*)((const u16*)h + i);
        }
        return;
    }
    if (b < nFill + nHb + 512) {  // -------- W1 [1024,512] -> W1T [1024,512] --------
        const int f = detect_blk((const u16*)W1, 1024 * 512, &sh);
        int sub = b - nFill - nHb;
        int half = sub >> 8, idx = sub & 255;
        const int bx = (idx & 15) * 32, by = (idx >> 4) * 32;
        const int koff = half * 512, noff = half * 512;
        const int tx = t & 31, ty = t >> 5;
        for (int i = ty; i < 32; i += 8) {
            long id = (long)(koff + by + i) * 512 + (bx + tx);
            tile[i][tx] = f ? f2b(((const float*)W1)[id]) : ((const u16*)W1)[id];
        }
        __syncthreads();
        for (int i = ty; i < 32; i += 8)
            W1T[(long)(noff + bx + i) * 512 + (by + tx)] = tile[tx][i];
        return;
    }
    if (b < nFill + nHb + 640) {  // -------- W2 [1024,128] -> W2T [256,512] --------
        const int f = detect_blk((const u16*)W2, 1024 * 128, &sh);
        int sub = b - nFill - nHb - 512;
        int half = sub >> 6, idx = sub & 63;
        const int bx = (idx & 3) * 32, by = (idx >> 2) * 32;
        const int koff = half * 512, noff = half * 128;
        const int tx = t & 31, ty = t >> 5;
        for (int i = ty; i < 32; i += 8) {
            long id = (long)(koff + by + i) * 128 + (bx + tx);
            tile[i][tx] = f ? f2b(((const float*)W2)[id]) : ((const u16*)W2)[id];
        }
        __syncthreads();
        for (int i = ty; i < 32; i += 8)
            W2T[(long)(noff + bx + i) * 512 + (by + tx)] = tile[tx][i];
        return;
    }
    // -------- biases + out-dtype flag --------
    {
        const int f1 = detect_blk((const u16*)b1, 512, &sh);
        for (int i = t; i < 512; i += 256)
            b1c[i] = f1 ? f2b(((const float*)b1)[i]) : ((const u16*)b1)[i];
        const int f2 = detect_blk((const u16*)b2, 128, &sh);
        if (t < 128)
            b2c[t] = f2 ? f2b(((const float*)b2)[t]) : ((const u16*)b2)[t];
        const int fh = detect_blk((const u16*)h, Nn * 512, &sh);
        if (t == 0) flags[0] = fh;
    }
}

// ================= 64x256 GEMM accumulate core (device) ==========================
// A tile 64 rows, B tile 256 rows (Bt row offset bobs). 4 waves split the 256
// cols: wave wv covers cols wv*64..+64, acc 4x4 = 16 MFMA per k-iter (m97's
// MFMA:barrier ratio). LDS 20 KB, BK=32 / 64B rows (proven layout).
// Per-output K order identical to previous cores -> bit-identical results.
__device__ __forceinline__ void gemm_acc256(const u16* __restrict__ A,
                                            const u16* __restrict__ Bt,
                                            long brow, int bobs,
                                            floatx4 acc[4][4], u16* lA, u16* lB) {
    const int tid = threadIdx.x;
    const int wv = tid >> 6;
    const int ln = tid & 63;
    const int lrow = ln >> 2;
    const int lk = (ln & 3) * 8;
    const int m0 = ln & 15;
    const int kq = (ln >> 4) * 8;
    const int wc = wv * 64;

#pragma unroll
    for (int i = 0; i < 4; ++i)
#pragma unroll
        for (int j = 0; j < 4; ++j) acc[i][j] = (floatx4){0.f, 0.f, 0.f, 0.f};

    for (int kt = 0; kt < 512; kt += 32) {
        // A: 4 chunks of 16 rows; wave wv stages chunk wv
        GLOAD_LDS16(A + (brow + wv * 16 + lrow) * 512 + kt + lk, lA + wv * 512);
        // B: 16 chunks of 16 rows; wave wv stages chunks wv, wv+4, wv+8, wv+12
#pragma unroll
        for (int i = 0; i < 4; ++i) {
            const int c = i * 4 + wv;
            GLOAD_LDS16(Bt + (long)(bobs + c * 16 + lrow) * 512 + kt + lk, lB + c * 512);
        }
        __syncthreads();
        bf16x8 af[4], bf[4];
#pragma unroll
        for (int i = 0; i < 4; ++i)
            af[i] = *(const bf16x8*)(lA + (i * 16 + m0) * 32 + kq);
#pragma unroll
        for (int j = 0; j < 4; ++j)
            bf[j] = *(const bf16x8*)(lB + (wc + j * 16 + m0) * 32 + kq);
#pragma unroll
        for (int i = 0; i < 4; ++i)
#pragma unroll
            for (int j = 0; j < 4; ++j)
                acc[i][j] = __builtin_amdgcn_mfma_f32_16x16x32_bf16(af[i], bf[j],
                                                                    acc[i][j], 0, 0, 0);
        __syncthreads();
    }
}

// ================= D2: GEMM1 64x256 ([C1s(bf16) | P1(fp8)] = Hb @ W1T^T) =========
// grid (ceil(M/64), 4) = 628 blocks (~2.4/CU), 16 MFMA/barrier-pair
__global__ __launch_bounds__(256) void k_gemm1_256(
    const u16* __restrict__ A, const u16* __restrict__ Bt,
    u16* __restrict__ C1s, u8* __restrict__ P1, int Mstore) {
    __shared__ __align__(16) u16 lA[64 * 32];
    __shared__ __align__(16) u16 lB[256 * 32];
    const int by = blockIdx.y;           // 0..3
    const int bcol = by * 256;
    const long brow = (long)blockIdx.x * 64;
    floatx4 acc[4][4];
    gemm_acc256(A, Bt, brow, bcol, acc, lA, lB);

    const int ln = threadIdx.x & 63;
    const int wv = threadIdx.x >> 6;
    const int wc = wv * 64;
    const int m0 = ln & 15;
    const int q4 = (ln >> 4) * 4;
    if (by < 2) {  // self half (cols 0..511) -> bf16, ld 512
#pragma unroll
        for (int i = 0; i < 4; ++i)
#pragma unroll
            for (int r = 0; r < 4; ++r) {
                long row = brow + i * 16 + q4 + r;
                if (row < Mstore) {
#pragma unroll
                    for (int j = 0; j < 4; ++j)
                        C1s[row * 512 + (bcol + wc + j * 16 + m0)] = f2b(acc[i][j][r]);
                }
            }
    } else {       // agg half (cols 512..1023) -> fp8 e4m3 bytes, ld 512
        const int coff = bcol - 512;
#pragma unroll
        for (int i = 0; i < 4; ++i)
#pragma unroll
            for (int r = 0; r < 4; ++r) {
                long row = brow + i * 16 + q4 + r;
                if (row < Mstore) {
#pragma unroll
                    for (int j = 0; j < 4; ++j) {
                        float v = acc[i][j][r];
                        int pk = __builtin_amdgcn_cvt_pk_fp8_f32(v, v, 0, false);
                        P1[row * 512 + (coff + wc + j * 16 + m0)] = (u8)(pk & 0xff);
                    }
                }
            }
    }
}

// ================= 64x128 GEMM core (device) — kept for GEMM2 ====================
__device__ __forceinline__ void gemm_acc64(const u16* __restrict__ A,
                                           const u16* __restrict__ Bt,
                                           long brow, int bobs,
                                           floatx4 acc[4][2], u16* lA, u16* lB) {
    const int tid = threadIdx.x;
    const int wv = tid >> 6;
    const int ln = tid & 63;
    const int lrow = ln >> 2;
    const int lk = (ln & 3) * 8;
    const int m0 = ln & 15;
    const int kq = (ln >> 4) * 8;
    const int wc = wv * 32;

#pragma unroll
    for (int i = 0; i < 4; ++i)
#pragma unroll
        for (int j = 0; j < 2; ++j) acc[i][j] = (floatx4){0.f, 0.f, 0.f, 0.f};

    for (int kt = 0; kt < 512; kt += 32) {
        GLOAD_LDS16(A + (brow + wv * 16 + lrow) * 512 + kt + lk, lA + wv * 512);
#pragma unroll
        for (int i = 0; i < 2; ++i) {
            const int c = i * 4 + wv;
            GLOAD_LDS16(Bt + (long)(bobs + c * 16 + lrow) * 512 + kt + lk, lB + c * 512);
        }
        __syncthreads();
        bf16x8 af[4], bf[2];
#pragma unroll
        for (int i = 0; i < 4; ++i)
            af[i] = *(const bf16x8*)(lA + (i * 16 + m0) * 32 + kq);
#pragma unroll
        for (int j = 0; j < 2; ++j)
            bf[j] = *(const bf16x8*)(lB + (wc + j * 16 + m0) * 32 + kq);
#pragma unroll
        for (int i = 0; i < 4; ++i)
#pragma unroll
            for (int j = 0; j < 2; ++j)
                acc[i][j] = __builtin_amdgcn_mfma_f32_16x16x32_bf16(af[i], bf[j],
                                                                    acc[i][j], 0, 0, 0);
        __syncthreads();
    }
}

// ================= D4: GEMM2 64x128 ([C2s|P2] = h1 @ W2T^T) ======================
__global__ __launch_bounds__(256) void k_gemm2_64(
    const u16* __restrict__ A, const u16* __restrict__ Bt,
    u16* __restrict__ C2s, u16* __restrict__ P2, int Mstore) {
    __shared__ __align__(16) u16 lA[64 * 32];
    __shared__ __align__(16) u16 lB[128 * 32];
    const long brow = (long)blockIdx.x * 64;
    floatx4 acc[4][2];
    gemm_acc64(A, Bt, brow, blockIdx.y * 128, acc, lA, lB);

    u16* C = blockIdx.y ? P2 : C2s;
    const int ln = threadIdx.x & 63;
    const int wv = threadIdx.x >> 6;
    const int wc = wv * 32;
    const int m0 = ln & 15;
    const int q4 = (ln >> 4) * 4;
#pragma unroll
    for (int i = 0; i < 4; ++i)
#pragma unroll
        for (int r = 0; r < 4; ++r) {
            long row = brow + i * 16 + q4 + r;
            if (row < Mstore) {
#pragma unroll
                for (int j = 0; j < 2; ++j)
                    C[row * 128 + (wc + j * 16 + m0)] = f2b(acc[i][j][r]);
            }
        }
}

// ================= D3: h1 = relu(C1s + mean(P1fp8[nbrs]) + b1) ===================
// wave-per-node: one dwordx2 per edge; 8-deep gather unroll
__global__ __launch_bounds__(256) void agg_h1(const u8* __restrict__ P1,
                                              const u16* __restrict__ C1s,
                                              const u16* __restrict__ b1c,
                                              const int* __restrict__ cnt,
                                              const int* __restrict__ bucket,
                                              const int* __restrict__ nspill,
                                              const int* __restrict__ spill,
                                              u16* __restrict__ h1, int Nn) {
    const int n = blockIdx.x * 4 + (threadIdx.x >> 6);
    const int l = threadIdx.x & 63;
    if (n >= Nn) return;
    const int c = cnt[n];
    const int inb = c < CAP ? c : CAP;
    const int* bk = bucket + (long)n * CAP;
    float a0 = 0.f, a1 = 0.f, a2 = 0.f, a3 = 0.f;
    float a4 = 0.f, a5 = 0.f, a6 = 0.f, a7 = 0.f;
    int e = 0;
    for (; e + 7 < inb; e += 8) {
        u32x2 w[8];
#pragma unroll
        for (int q = 0; q < 8; ++q) {
            int s = bk[e + q];
            w[q] = *(const u32x2*)(P1 + (long)s * 512 + l * 8);
        }
#pragma unroll
        for (int q = 0; q < 8; ++q) {
            floatx2 f0 = __builtin_amdgcn_cvt_pk_f32_fp8(w[q][0], false);
            floatx2 f1 = __builtin_amdgcn_cvt_pk_f32_fp8(w[q][0], true);
            floatx2 f2 = __builtin_amdgcn_cvt_pk_f32_fp8(w[q][1], false);
            floatx2 f3 = __builtin_amdgcn_cvt_pk_f32_fp8(w[q][1], true);
            a0 += f0[0]; a1 += f0[1]; a2 += f1[0]; a3 += f1[1];
            a4 += f2[0]; a5 += f2[1]; a6 += f3[0]; a7 += f3[1];
        }
    }
    for (; e < inb; ++e) {
        int s = bk[e];
        u32x2 w = *(const u32x2*)(P1 + (long)s * 512 + l * 8);
        floatx2 f0 = __builtin_amdgcn_cvt_pk_f32_fp8(w[0], false);
        floatx2 f1 = __builtin_amdgcn_cvt_pk_f32_fp8(w[0], true);
        floatx2 f2 = __builtin_amdgcn_cvt_pk_f32_fp8(w[1], false);
        floatx2 f3 = __builtin_amdgcn_cvt_pk_f32_fp8(w[1], true);
        a0 += f0[0]; a1 += f0[1]; a2 += f1[0]; a3 += f1[1];
        a4 += f2[0]; a5 += f2[1]; a6 += f3[0]; a7 += f3[1];
    }
    const int ns = *nspill;             // 0 in practice
    if (ns > 0) {
        int lim = ns < SPILLMAX ? ns : SPILLMAX;
        for (int q = 0; q < lim; ++q) {
            if (spill[2 * q] == n) {
                int s = spill[2 * q + 1];
                u32x2 w = *(const u32x2*)(P1 + (long)s * 512 + l * 8);
                floatx2 f0 = __builtin_amdgcn_cvt_pk_f32_fp8(w[0], false);
                floatx2 f1 = __builtin_amdgcn_cvt_pk_f32_fp8(w[0], true);
                floatx2 f2 = __builtin_amdgcn_cvt_pk_f32_fp8(w[1], false);
                floatx2 f3 = __builtin_amdgcn_cvt_pk_f32_fp8(w[1], true);
                a0 += f0[0]; a1 += f0[1]; a2 += f1[0]; a3 += f1[1];
                a4 += f2[0]; a5 += f2[1]; a6 += f3[0]; a7 += f3[1];
            }
        }
    }
    float inv = 1.0f / (float)(c > 1 ? c : 1);
    us8 sf = *(const us8*)(C1s + (long)n * 512 + l * 8);
    us8 bv = *(const us8*)(b1c + l * 8);
    us8 o;
    o[0] = f2b(fmaxf(b2f(sf[0]) + a0 * inv + b2f(bv[0]), 0.f));
    o[1] = f2b(fmaxf(b2f(sf[1]) + a1 * inv + b2f(bv[1]), 0.f));
    o[2] = f2b(fmaxf(b2f(sf[2]) + a2 * inv + b2f(bv[2]), 0.f));
    o[3] = f2b(fmaxf(b2f(sf[3]) + a3 * inv + b2f(bv[3]), 0.f));
    o[4] = f2b(fmaxf(b2f(sf[4]) + a4 * inv + b2f(bv[4]), 0.f));
    o[5] = f2b(fmaxf(b2f(sf[5]) + a5 * inv + b2f(bv[5]), 0.f));
    o[6] = f2b(fmaxf(b2f(sf[6]) + a6 * inv + b2f(bv[6]), 0.f));
    o[7] = f2b(fmaxf(b2f(sf[7]) + a7 * inv + b2f(bv[7]), 0.f));
    *(us8*)(h1 + (long)n * 512 + l * 8) = o;
}

// ================= D5: out = C2s + mean(P2[nbrs]) + b2 ===========================
__global__ __launch_bounds__(256) void agg_out(const u16* __restrict__ P2,
                                               const u16* __restrict__ C2s,
                                               const u16* __restrict__ b2c,
                                               const int* __restrict__ cnt,
                                               const int* __restrict__ bucket,
                                               const int* __restrict__ nspill,
                                               const int* __restrict__ spill,
                                               void* __restrict__ outv, int Nn,
                                               const int* __restrict__ flags) {
    const int n = blockIdx.x * 4 + (threadIdx.x >> 6);
    const int l = threadIdx.x & 63;
    if (n >= Nn) return;
    const int c = cnt[n];
    const int inb = c < CAP ? c : CAP;
    const int* bk = bucket + (long)n * CAP;
    float a0 = 0.f, a1 = 0.f;
    int e = 0;
    for (; e + 3 < inb; e += 4) {
        int s0 = bk[e], s1 = bk[e + 1], s2 = bk[e + 2], s3 = bk[e + 3];
        us2 v0 = *(const us2*)(P2 + (long)s0 * 128 + l * 2);
        us2 v1 = *(const us2*)(P2 + (long)s1 * 128 + l * 2);
        us2 v2 = *(const us2*)(P2 + (long)s2 * 128 + l * 2);
        us2 v3 = *(const us2*)(P2 + (long)s3 * 128 + l * 2);
        a0 += (b2f(v0[0]) + b2f(v1[0])) + (b2f(v2[0]) + b2f(v3[0]));
        a1 += (b2f(v0[1]) + b2f(v1[1])) + (b2f(v2[1]) + b2f(v3[1]));
    }
    for (; e < inb; ++e) {
        int s0 = bk[e];
        us2 v0 = *(const us2*)(P2 + (long)s0 * 128 + l * 2);
        a0 += b2f(v0[0]); a1 += b2f(v0[1]);
    }
    const int ns = *nspill;
    if (ns > 0) {
        int lim = ns < SPILLMAX ? ns : SPILLMAX;
        for (int q = 0; q < lim; ++q) {
            if (spill[2 * q] == n) {
                int s0 = spill[2 * q + 1];
                us2 v0 = *(const us2*)(P2 + (long)s0 * 128 + l * 2);
                a0 += b2f(v0[0]); a1 += b2f(v0[1]);
            }
        }
    }
    float inv = 1.0f / (float)(c > 1 ? c : 1);
    us2 sf = *(const us2*)(C2s + (long)n * 128 + l * 2);
    us2 bv = *(const us2*)(b2c + l * 2);
    float o0 = b2f(sf[0]) + a0 * inv + b2f(bv[0]);
    float o1 = b2f(sf[1]) + a1 * inv + b2f(bv[1]);
    if (flags[0]) {
        float* o = (float*)outv + (long)n * 128 + l * 2;
        o[0] = o0; o[1] = o1;
    } else {
        us2 ob; ob[0] = f2b(o0); ob[1] = f2b(o1);
        *(us2*)((u16*)outv + (long)n * 128 + l * 2) = ob;
    }
}

// ================= launch ========================================================
extern "C" void kernel_launch(void* const* d_in, const int* in_sizes, int n_in,
                              void* d_out, int out_size, void* d_ws, size_t ws_size,
                              hipStream_t stream) {
    const int D = 512, NCLS = 128;
    const int Nn = in_sizes[0] / D;            // 10000
    const int E  = in_sizes[5];                // 160000
    const int mtiles = (Nn + 127) / 128;       // 79
    const int mt64 = (Nn + 63) / 64;           // 157
    const int Mpad = mtiles * 128;             // 10112
    const int nFill = (E + 255) / 256;         // 625
    const int nHb = (Nn * D / 8 + 255) / 256;  // 2500

    const int* src = (const int*)d_in[5];
    const int* dst = (const int*)d_in[6];

    char* p = (char*)d_ws;
    u16* Hb  = (u16*)p; p += (size_t)Mpad * D * 2;
    u16* h1  = (u16*)p; p += (size_t)Mpad * D * 2;
    u16* C1s = (u16*)p; p += (size_t)Mpad * D * 2;
    u8*  P1  = (u8*)p;  p += (size_t)Mpad * D;        // fp8 e4m3
    u16* C2s = (u16*)p; p += (size_t)Mpad * NCLS * 2;
    u16* P2  = (u16*)p; p += (size_t)Mpad * NCLS * 2;
    u16* W1T = (u16*)p; p += (size_t)1024 * D * 2;
    u16* W2T = (u16*)p; p += (size_t)256 * D * 2;
    u16* b1c = (u16*)p; p += 1024;
    u16* b2c = (u16*)p; p += 1024;
    int* flags  = (int*)p; p += 256;
    int* cnt    = (int*)p; p += (size_t)(Nn + 60) * 4;
    int* nspill = cnt + Nn;
    int* bucket = (int*)p; p += (size_t)Nn * CAP * 4;
    int* spill  = (int*)p; p += (size_t)SPILLMAX * 2 * 4;

    hipMemsetAsync(cnt, 0, (size_t)(Nn + 60) * 4, stream);

    // D1: buckets + all conversions
    k_d1<<<nFill + nHb + 641, 256, 0, stream>>>(
        src, dst, E, Nn, cnt, bucket, nspill, spill,
        d_in[0], d_in[1], d_in[2], d_in[3], d_in[4],
        Hb, W1T, W2T, b1c, b2c, flags, nFill, nHb);

    // D2: [C1s(bf16) | P1(fp8)] = Hb @ W1T^T  [64x256 tiles, 628 blocks]
    k_gemm1_256<<<dim3(mt64, 4), 256, 0, stream>>>(Hb, W1T, C1s, P1, Nn);

    // D3: h1 = relu(C1s + mean(P1[nbrs]) + b1)  [wave-per-node]
    agg_h1<<<(Nn + 3) / 4, 256, 0, stream>>>(P1, C1s, b1c, cnt, bucket,
                                             nspill, spill, h1, Nn);

    // D4: [C2s|P2] = h1 @ W2T^T  [64x128 tiles, 314 blocks]
    k_gemm2_64<<<dim3(mt64, 2), 256, 0, stream>>>(h1, W2T, C2s, P2, Nn);

    // D5: out = C2s + mean(P2[nbrs]) + b2
    agg_out<<<(Nn + 3) / 4, 256, 0, stream>>>(P2, C2s, b2c, cnt, bucket,
                                              nspill, spill, d_out, Nn, flags);
}